// Round 2
// baseline (1937.949 us; speedup 1.0000x reference)
//
#include <hip/hip_runtime.h>
#include <hip/hip_bf16.h>
#include <math.h>

#define D_MODEL 768
#define D_STATE 64
#define D_CONV 4
#define D_INNER 1536
#define HEADDIM 64
#define NHEADS 24
#define RANK 8
#define D_IN_PROJ 3224   // 2*1536 + 2*64 + 24
#define CONV_DIM 1664    // 1536 + 128
#define BSZ 2
#define SEQ 1024
#define NROWS (BSZ*SEQ)  // 2048
#define SCALE_LORA 2.0f  // 16/8

// ---------------- helpers ----------------

__device__ inline float waveReduceSum(float v) {
#pragma unroll
    for (int m = 32; m; m >>= 1) v += __shfl_xor(v, m, 64);
    return v;
}

// block reduce (blockDim.x <= 512, multiple of 64); all threads get total
template <int NWAVES>
__device__ inline float blockReduceSum(float v) {
    __shared__ float tmp[NWAVES];
    int lane = threadIdx.x & 63, wid = threadIdx.x >> 6;
    v = waveReduceSum(v);
    if (lane == 0) tmp[wid] = v;
    __syncthreads();
    float tot = 0.f;
#pragma unroll
    for (int i = 0; i < NWAVES; i++) tot += tmp[i];
    return tot;
}

__device__ inline float sigmoidf_(float x) { return 1.f / (1.f + expf(-x)); }

// ---------------- weight build ----------------

__global__ void build_w_in_kernel(const float* __restrict__ base,
                                  const float* __restrict__ lA,   // [RANK][D_MODEL]
                                  const float* __restrict__ lB,   // [D_IN_PROJ][RANK]
                                  float* __restrict__ W) {
    int idx = blockIdx.x * blockDim.x + threadIdx.x;
    if (idx >= D_IN_PROJ * D_MODEL) return;
    int r = idx / D_MODEL, c = idx - r * D_MODEL;
    float s = 0.f;
#pragma unroll
    for (int k = 0; k < RANK; k++) s += lB[r * RANK + k] * lA[k * D_MODEL + c];
    W[idx] = base[idx] + SCALE_LORA * s;
}

__global__ void build_w_out_kernel(const float* __restrict__ base,
                                   const float* __restrict__ lA,   // [RANK][D_INNER]
                                   const float* __restrict__ lB,   // [D_MODEL][RANK]
                                   float* __restrict__ W) {
    int idx = blockIdx.x * blockDim.x + threadIdx.x;
    if (idx >= D_MODEL * D_INNER) return;
    int r = idx / D_INNER, c = idx - r * D_INNER;
    float s = 0.f;
#pragma unroll
    for (int k = 0; k < RANK; k++) s += lB[r * RANK + k] * lA[k * D_INNER + c];
    W[idx] = base[idx] + SCALE_LORA * s;
}

// ---------------- rmsnorm + rope ----------------
// grid: 2048 rows, block 384 threads (one thread per even/odd pair)
__global__ __launch_bounds__(384) void rmsrope_kernel(
    const float* __restrict__ x, const float* __restrict__ w,
    float* __restrict__ out, int loop_i) {
    int row = blockIdx.x;
    const float* xr = x + (size_t)row * D_MODEL;
    int j = threadIdx.x;            // pair index 0..383
    float x0 = xr[2 * j], x1 = xr[2 * j + 1];
    float ss = blockReduceSum<6>(x0 * x0 + x1 * x1);
    float sc = rsqrtf(ss * (1.f / D_MODEL) + 1e-6f);
    float y0 = x0 * sc * w[2 * j];
    float y1 = x1 * sc * w[2 * j + 1];
    // inv_freq = 10000^(-2j/768) = exp(-2j * ln(10000)/768)
    float ang = (float)loop_i * expf((float)(2 * j) * (-9.210340371976184f / (float)D_MODEL));
    float c = cosf(ang), sn = sinf(ang);
    float* orow = out + (size_t)row * D_MODEL;
    orow[2 * j]     = y0 * c - y1 * sn;
    orow[2 * j + 1] = y1 * c + y0 * sn;
}

// ---------------- f32 tiled GEMM: C[M][N] = A[M][K] . B[N][K]^T ----------------
// 64x64 tile, BK=32, 256 threads, 4x4 micro-tile.
// If gate != nullptr: C = acc + gate[n]*xp[m*N+n]   (GEMM2 epilogue)
#define BM 64
#define BN 64
#define BKK 32
__global__ __launch_bounds__(256) void gemm_nt_kernel(
    const float* __restrict__ A, const float* __restrict__ B,
    float* __restrict__ C, int M, int N, int K,
    const float* __restrict__ xp, const float* __restrict__ gate) {
    __shared__ float As[BM][BKK + 1];
    __shared__ float Bs[BN][BKK + 1];
    int tid = threadIdx.x;
    int n0 = blockIdx.x * BN;
    int m0 = blockIdx.y * BM;
    int tx = tid & 15, ty = tid >> 4;
    float acc[4][4] = {};
    for (int k0 = 0; k0 < K; k0 += BKK) {
#pragma unroll
        for (int s = 0; s < 2; s++) {
            int slot = tid + s * 256;          // 512 float4 slots per operand
            int r = slot >> 3, kc = (slot & 7) << 2;
            float4 av = *reinterpret_cast<const float4*>(&A[(size_t)(m0 + r) * K + k0 + kc]);
            As[r][kc] = av.x; As[r][kc + 1] = av.y; As[r][kc + 2] = av.z; As[r][kc + 3] = av.w;
            int nr = n0 + r;
            float4 bv = make_float4(0.f, 0.f, 0.f, 0.f);
            if (nr < N) bv = *reinterpret_cast<const float4*>(&B[(size_t)nr * K + k0 + kc]);
            Bs[r][kc] = bv.x; Bs[r][kc + 1] = bv.y; Bs[r][kc + 2] = bv.z; Bs[r][kc + 3] = bv.w;
        }
        __syncthreads();
#pragma unroll
        for (int kk = 0; kk < BKK; kk++) {
            float a[4], b[4];
#pragma unroll
            for (int e = 0; e < 4; e++) a[e] = As[ty * 4 + e][kk];
#pragma unroll
            for (int e = 0; e < 4; e++) b[e] = Bs[tx * 4 + e][kk];
#pragma unroll
            for (int i = 0; i < 4; i++)
#pragma unroll
                for (int jj = 0; jj < 4; jj++)
                    acc[i][jj] = fmaf(a[i], b[jj], acc[i][jj]);
        }
        __syncthreads();
    }
#pragma unroll
    for (int i = 0; i < 4; i++) {
        int m = m0 + ty * 4 + i;
#pragma unroll
        for (int jj = 0; jj < 4; jj++) {
            int n = n0 + tx * 4 + jj;
            if (n < N) {
                float v = acc[i][jj];
                if (gate) v += gate[n] * xp[(size_t)m * N + n];
                C[(size_t)m * N + n] = v;
            }
        }
    }
}

// ---------------- dt / dA ----------------
__global__ void dt_kernel(const float* __restrict__ zx, const float* __restrict__ dt_bias,
                          const float* __restrict__ A_log,
                          float* __restrict__ dtb, float* __restrict__ dAb) {
    int idx = blockIdx.x * blockDim.x + threadIdx.x;   // NROWS*NHEADS
    if (idx >= NROWS * NHEADS) return;
    int row = idx / NHEADS, h = idx - row * NHEADS;
    float raw = zx[(size_t)row * D_IN_PROJ + (D_INNER + CONV_DIM) + h] + dt_bias[h];
    float dt = raw > 20.f ? raw : log1pf(expf(raw));
    float A = -expf(A_log[h]);
    dtb[idx] = dt;
    dAb[idx] = expf(dt * A);
}

// ---------------- depthwise causal conv + silu ----------------
__global__ void conv_kernel(const float* __restrict__ zx, const float* __restrict__ cw,
                            const float* __restrict__ cb, float* __restrict__ xbc) {
    int idx = blockIdx.x * blockDim.x + threadIdx.x;   // BSZ*SEQ*CONV_DIM
    if (idx >= BSZ * SEQ * CONV_DIM) return;
    int c = idx % CONV_DIM;
    int l = (idx / CONV_DIM) % SEQ;
    int b = idx / (CONV_DIM * SEQ);
    const float* base = zx + (size_t)b * SEQ * D_IN_PROJ + D_INNER + c;
    float acc = cb[c];
#pragma unroll
    for (int t = 0; t < 4; t++) {
        int ll = l - 3 + t;
        if (ll >= 0) acc = fmaf(cw[c * 4 + t], base[(size_t)ll * D_IN_PROJ], acc);
    }
    xbc[idx] = acc * sigmoidf_(acc);
}

// ---------------- sequential SSM scan ----------------
// grid: BSZ*NHEADS*16 blocks; block 256 = 4 waves; wave handles one p, lane = n.
__global__ __launch_bounds__(256) void scan_kernel(
    const float* __restrict__ xbc,   // [NROWS][CONV_DIM]
    const float* __restrict__ dtb,   // [NROWS][NHEADS]
    const float* __restrict__ dAb,
    const float* __restrict__ Dp,    // [NHEADS]
    float* __restrict__ y) {         // [NROWS][D_INNER]
    int blk = blockIdx.x;
    int pg = blk & 15;
    int t1 = blk >> 4;
    int h = t1 % NHEADS;
    int b = t1 / NHEADS;
    int lane = threadIdx.x & 63;
    int p = pg * 4 + (threadIdx.x >> 6);
    float D_h = Dp[h];
    float s = 0.f;
    const int xcol = h * HEADDIM + p;
    for (int t = 0; t < SEQ; t++) {
        size_t row = (size_t)(b * SEQ + t);
        const float* xr = xbc + row * CONV_DIM;
        float dA = dAb[row * NHEADS + h];
        float dt = dtb[row * NHEADS + h];
        float Bv = xr[D_INNER + lane];
        float Cv = xr[D_INNER + D_STATE + lane];
        float xv = xr[xcol];
        s = fmaf(dA, s, dt * xv * Bv);
        float yp = Cv * s;
#pragma unroll
        for (int m = 1; m < 64; m <<= 1) yp += __shfl_xor(yp, m, 64);
        if (lane == 0) y[row * D_INNER + xcol] = fmaf(D_h, xv, yp);
    }
}

// ---------------- gated rmsnorm (in place on y) ----------------
__global__ __launch_bounds__(256) void gatenorm_kernel(
    float* __restrict__ y, const float* __restrict__ zx,
    const float* __restrict__ w) {
    int row = blockIdx.x;
    const float* z = zx + (size_t)row * D_IN_PROJ;
    float* yr = y + (size_t)row * D_INNER;
    float g[6];
    float ss = 0.f;
#pragma unroll
    for (int e = 0; e < 6; e++) {
        int idx = threadIdx.x + e * 256;
        float zv = z[idx];
        float gv = yr[idx] * (zv * sigmoidf_(zv));
        g[e] = gv;
        ss += gv * gv;
    }
    ss = blockReduceSum<4>(ss);
    float sc = rsqrtf(ss * (1.f / D_INNER) + 1e-6f);
#pragma unroll
    for (int e = 0; e < 6; e++) {
        int idx = threadIdx.x + e * 256;
        yr[idx] = g[e] * sc * w[idx];
    }
}

// ---------------- launch ----------------
extern "C" void kernel_launch(void* const* d_in, const int* in_sizes, int n_in,
                              void* d_out, int out_size, void* d_ws, size_t ws_size,
                              hipStream_t stream) {
    const float* x        = (const float*)d_in[0];
    const float* x_prompt = (const float*)d_in[1];
    const float* in_base  = (const float*)d_in[2];
    const float* lA_in    = (const float*)d_in[3];
    const float* lB_in    = (const float*)d_in[4];
    const float* conv_w   = (const float*)d_in[5];
    const float* conv_b   = (const float*)d_in[6];
    const float* dt_bias  = (const float*)d_in[7];
    const float* A_log    = (const float*)d_in[8];
    const float* D_param  = (const float*)d_in[9];
    const float* gnw      = (const float*)d_in[10];
    const float* out_base = (const float*)d_in[11];
    const float* lA_out   = (const float*)d_in[12];
    const float* lB_out   = (const float*)d_in[13];
    const float* loop_nw  = (const float*)d_in[14];
    const float* gate     = (const float*)d_in[15];
    float* out = (float*)d_out;

    float* ws = (float*)d_ws;
    float* W_in  = ws;                                 // 3224*768
    float* W_out = W_in  + (size_t)D_IN_PROJ * D_MODEL; // 768*1536
    float* hbuf  = W_out + (size_t)D_MODEL * D_INNER;   // 2048*768
    float* zx    = hbuf  + (size_t)NROWS * D_MODEL;     // 2048*3224
    float* xbc   = zx    + (size_t)NROWS * D_IN_PROJ;   // 2048*1664
    float* dtb   = xbc   + (size_t)NROWS * CONV_DIM;    // 2048*24
    float* dAb   = dtb   + (size_t)NROWS * NHEADS;      // 2048*24
    float* ybuf  = dAb   + (size_t)NROWS * NHEADS;      // 2048*1536

    // weights (loop-invariant)
    build_w_in_kernel<<<(D_IN_PROJ * D_MODEL + 255) / 256, 256, 0, stream>>>(in_base, lA_in, lB_in, W_in);
    build_w_out_kernel<<<(D_MODEL * D_INNER + 255) / 256, 256, 0, stream>>>(out_base, lA_out, lB_out, W_out);

    for (int i = 0; i < 2; i++) {   // n_loops = 2 (fixed by setup_inputs)
        const float* xsrc = (i == 0) ? x : out;
        rmsrope_kernel<<<NROWS, 384, 0, stream>>>(xsrc, loop_nw, hbuf, i);

        dim3 g1((D_IN_PROJ + BN - 1) / BN, NROWS / BM);
        gemm_nt_kernel<<<g1, 256, 0, stream>>>(hbuf, W_in, zx, NROWS, D_IN_PROJ, D_MODEL,
                                               nullptr, nullptr);

        dt_kernel<<<(NROWS * NHEADS + 255) / 256, 256, 0, stream>>>(zx, dt_bias, A_log, dtb, dAb);
        conv_kernel<<<(BSZ * SEQ * CONV_DIM + 255) / 256, 256, 0, stream>>>(zx, conv_w, conv_b, xbc);

        scan_kernel<<<BSZ * NHEADS * 16, 256, 0, stream>>>(xbc, dtb, dAb, D_param, ybuf);

        gatenorm_kernel<<<NROWS, 256, 0, stream>>>(ybuf, zx, gnw);

        dim3 g2(D_MODEL / BN, NROWS / BM);
        gemm_nt_kernel<<<g2, 256, 0, stream>>>(ybuf, W_out, out, NROWS, D_MODEL, D_INNER,
                                               x_prompt, gate);
    }
}

// Round 3
// 1446.186 us; speedup vs baseline: 1.3400x; 1.3400x over previous
//
#include <hip/hip_runtime.h>
#include <hip/hip_bf16.h>
#include <math.h>

#define D_MODEL 768
#define D_STATE 64
#define D_CONV 4
#define D_INNER 1536
#define HEADDIM 64
#define NHEADS 24
#define RANK 8
#define D_IN_PROJ 3224   // 2*1536 + 2*64 + 24
#define CONV_DIM 1664    // 1536 + 128
#define BSZ 2
#define SEQ 1024
#define NROWS (BSZ*SEQ)  // 2048
#define SCALE_LORA 2.0f  // 16/8
#define LC 64            // chunk length
#define NCHUNK (SEQ/LC)  // 16

// ---------------- helpers ----------------

__device__ inline float waveReduceSum(float v) {
#pragma unroll
    for (int m = 32; m; m >>= 1) v += __shfl_xor(v, m, 64);
    return v;
}

template <int NWAVES>
__device__ inline float blockReduceSum(float v) {
    __shared__ float tmp[NWAVES];
    int lane = threadIdx.x & 63, wid = threadIdx.x >> 6;
    v = waveReduceSum(v);
    if (lane == 0) tmp[wid] = v;
    __syncthreads();
    float tot = 0.f;
#pragma unroll
    for (int i = 0; i < NWAVES; i++) tot += tmp[i];
    return tot;
}

__device__ inline float sigmoidf_(float x) { return 1.f / (1.f + expf(-x)); }

// ---------------- weight build ----------------

__global__ void build_w_in_kernel(const float* __restrict__ base,
                                  const float* __restrict__ lA,
                                  const float* __restrict__ lB,
                                  float* __restrict__ W) {
    int idx = blockIdx.x * blockDim.x + threadIdx.x;
    if (idx >= D_IN_PROJ * D_MODEL) return;
    int r = idx / D_MODEL, c = idx - r * D_MODEL;
    float s = 0.f;
#pragma unroll
    for (int k = 0; k < RANK; k++) s += lB[r * RANK + k] * lA[k * D_MODEL + c];
    W[idx] = base[idx] + SCALE_LORA * s;
}

__global__ void build_w_out_kernel(const float* __restrict__ base,
                                   const float* __restrict__ lA,
                                   const float* __restrict__ lB,
                                   float* __restrict__ W) {
    int idx = blockIdx.x * blockDim.x + threadIdx.x;
    if (idx >= D_MODEL * D_INNER) return;
    int r = idx / D_INNER, c = idx - r * D_INNER;
    float s = 0.f;
#pragma unroll
    for (int k = 0; k < RANK; k++) s += lB[r * RANK + k] * lA[k * D_INNER + c];
    W[idx] = base[idx] + SCALE_LORA * s;
}

// ---------------- rmsnorm + rope ----------------
__global__ __launch_bounds__(384) void rmsrope_kernel(
    const float* __restrict__ x, const float* __restrict__ w,
    float* __restrict__ out, int loop_i) {
    int row = blockIdx.x;
    const float* xr = x + (size_t)row * D_MODEL;
    int j = threadIdx.x;
    float x0 = xr[2 * j], x1 = xr[2 * j + 1];
    float ss = blockReduceSum<6>(x0 * x0 + x1 * x1);
    float sc = rsqrtf(ss * (1.f / D_MODEL) + 1e-6f);
    float y0 = x0 * sc * w[2 * j];
    float y1 = x1 * sc * w[2 * j + 1];
    float ang = (float)loop_i * expf((float)(2 * j) * (-9.210340371976184f / (float)D_MODEL));
    float c = cosf(ang), sn = sinf(ang);
    float* orow = out + (size_t)row * D_MODEL;
    orow[2 * j]     = y0 * c - y1 * sn;
    orow[2 * j + 1] = y1 * c + y0 * sn;
}

// ---------------- f32 tiled GEMM: C[M][N] = A[M][K] . B[N][K]^T ----------------
#define BM 64
#define BN 64
#define BKK 32
__global__ __launch_bounds__(256) void gemm_nt_kernel(
    const float* __restrict__ A, const float* __restrict__ B,
    float* __restrict__ C, int M, int N, int K,
    const float* __restrict__ xp, const float* __restrict__ gate) {
    __shared__ float As[BM][BKK + 1];
    __shared__ float Bs[BN][BKK + 1];
    int tid = threadIdx.x;
    int n0 = blockIdx.x * BN;
    int m0 = blockIdx.y * BM;
    int tx = tid & 15, ty = tid >> 4;
    float acc[4][4] = {};
    for (int k0 = 0; k0 < K; k0 += BKK) {
#pragma unroll
        for (int s = 0; s < 2; s++) {
            int slot = tid + s * 256;
            int r = slot >> 3, kc = (slot & 7) << 2;
            float4 av = *reinterpret_cast<const float4*>(&A[(size_t)(m0 + r) * K + k0 + kc]);
            As[r][kc] = av.x; As[r][kc + 1] = av.y; As[r][kc + 2] = av.z; As[r][kc + 3] = av.w;
            int nr = n0 + r;
            float4 bv = make_float4(0.f, 0.f, 0.f, 0.f);
            if (nr < N) bv = *reinterpret_cast<const float4*>(&B[(size_t)nr * K + k0 + kc]);
            Bs[r][kc] = bv.x; Bs[r][kc + 1] = bv.y; Bs[r][kc + 2] = bv.z; Bs[r][kc + 3] = bv.w;
        }
        __syncthreads();
#pragma unroll
        for (int kk = 0; kk < BKK; kk++) {
            float a[4], b[4];
#pragma unroll
            for (int e = 0; e < 4; e++) a[e] = As[ty * 4 + e][kk];
#pragma unroll
            for (int e = 0; e < 4; e++) b[e] = Bs[tx * 4 + e][kk];
#pragma unroll
            for (int i = 0; i < 4; i++)
#pragma unroll
                for (int jj = 0; jj < 4; jj++)
                    acc[i][jj] = fmaf(a[i], b[jj], acc[i][jj]);
        }
        __syncthreads();
    }
#pragma unroll
    for (int i = 0; i < 4; i++) {
        int m = m0 + ty * 4 + i;
#pragma unroll
        for (int jj = 0; jj < 4; jj++) {
            int n = n0 + tx * 4 + jj;
            if (n < N) {
                float v = acc[i][jj];
                if (gate) v += gate[n] * xp[(size_t)m * N + n];
                C[(size_t)m * N + n] = v;
            }
        }
    }
}

// ---------------- dt / dA ----------------
__global__ void dt_kernel(const float* __restrict__ zx, const float* __restrict__ dt_bias,
                          const float* __restrict__ A_log,
                          float* __restrict__ dtb, float* __restrict__ dAb) {
    int idx = blockIdx.x * blockDim.x + threadIdx.x;
    if (idx >= NROWS * NHEADS) return;
    int row = idx / NHEADS, h = idx - row * NHEADS;
    float raw = zx[(size_t)row * D_IN_PROJ + (D_INNER + CONV_DIM) + h] + dt_bias[h];
    float dt = raw > 20.f ? raw : log1pf(expf(raw));
    float A = -expf(A_log[h]);
    dtb[idx] = dt;
    dAb[idx] = expf(dt * A);
}

// ---------------- depthwise causal conv + silu ----------------
__global__ void conv_kernel(const float* __restrict__ zx, const float* __restrict__ cw,
                            const float* __restrict__ cb, float* __restrict__ xbc) {
    int idx = blockIdx.x * blockDim.x + threadIdx.x;
    if (idx >= BSZ * SEQ * CONV_DIM) return;
    int c = idx % CONV_DIM;
    int l = (idx / CONV_DIM) % SEQ;
    int b = idx / (CONV_DIM * SEQ);
    const float* base = zx + (size_t)b * SEQ * D_IN_PROJ + D_INNER + c;
    float acc = cb[c];
#pragma unroll
    for (int t = 0; t < 4; t++) {
        int ll = l - 3 + t;
        if (ll >= 0) acc = fmaf(cw[c * 4 + t], base[(size_t)ll * D_IN_PROJ], acc);
    }
    xbc[idx] = acc * sigmoidf_(acc);
}

// ---------------- chunked SSM scan ----------------
// Pass A0: cumulative decay per chunk. cumA[t] = prod_{u=t0..t0+t} dA_u (inclusive).
__global__ void cuma_kernel(const float* __restrict__ dAb, float* __restrict__ cumA) {
    int id = blockIdx.x * blockDim.x + threadIdx.x;   // (b*NHEADS+h)*NCHUNK + c
    if (id >= BSZ * NHEADS * NCHUNK) return;
    int c = id % NCHUNK;
    int bh = id / NCHUNK;
    int h = bh % NHEADS, b = bh / NHEADS;
    float r = 1.f;
    for (int t = 0; t < LC; t++) {
        size_t row = (size_t)(b * SEQ + c * LC + t);
        r *= dAb[row * NHEADS + h];
        cumA[(size_t)id * LC + t] = r;
    }
}

// Pass A: per-chunk scan from h=0. Writes intra-chunk y and chunk-final state F.
// grid: (b,h,chunk,pgroup) = 2*24*16*16 = 12288 blocks; block 256 = 4 waves (one p each), lane = n.
__global__ __launch_bounds__(256) void scan_chunk_kernel(
    const float* __restrict__ xbc,
    const float* __restrict__ dtb,
    const float* __restrict__ dAb,
    const float* __restrict__ Dp,
    float* __restrict__ y,
    float* __restrict__ Fbuf) {     // [(b,h,chunk)][p][n]
    int blk = blockIdx.x;
    int pg = blk & 15;
    int c  = (blk >> 4) & (NCHUNK - 1);
    int bh = blk >> 8;                  // b*NHEADS + h
    int h = bh % NHEADS;
    int b = bh / NHEADS;
    int lane = threadIdx.x & 63;
    int p = pg * 4 + (threadIdx.x >> 6);
    float D_h = Dp[h];
    float s = 0.f;
    const int xcol = h * HEADDIM + p;
    const int t0 = c * LC;
    for (int t = 0; t < LC; t++) {
        size_t row = (size_t)(b * SEQ + t0 + t);
        const float* xr = xbc + row * CONV_DIM;
        float dA = dAb[row * NHEADS + h];
        float dt = dtb[row * NHEADS + h];
        float Bv = xr[D_INNER + lane];
        float Cv = xr[D_INNER + D_STATE + lane];
        float xv = xr[xcol];
        s = fmaf(dA, s, dt * xv * Bv);
        float yp = Cv * s;
#pragma unroll
        for (int m = 1; m < 64; m <<= 1) yp += __shfl_xor(yp, m, 64);
        if (lane == 0) y[row * D_INNER + xcol] = fmaf(D_h, xv, yp);
    }
    Fbuf[((size_t)(bh * NCHUNK + c) * HEADDIM + p) * D_STATE + lane] = s;
}

// Pass B: sequential combine over chunks -> per-chunk initial states.
// grid: 48 blocks (b,h); each thread owns 16 (p,n) states.
__global__ __launch_bounds__(256) void combine_kernel(
    const float* __restrict__ Fbuf, const float* __restrict__ cumA,
    float* __restrict__ Hinit) {
    int bh = blockIdx.x;
    int tid = threadIdx.x;
    float H[16];
#pragma unroll
    for (int k = 0; k < 16; k++) H[k] = 0.f;
    for (int c = 0; c < NCHUNK; c++) {
        size_t base = (size_t)(bh * NCHUNK + c) * (HEADDIM * D_STATE);
        float pA = cumA[(size_t)(bh * NCHUNK + c) * LC + (LC - 1)];
#pragma unroll
        for (int k = 0; k < 16; k++) {
            size_t idx = base + tid + k * 256;
            Hinit[idx] = H[k];
            H[k] = fmaf(pA, H[k], Fbuf[idx]);
        }
    }
}

// Pass C: y[t,p] += sum_n (C[t,n]*cumA[t]) * Hinit[p,n]   (64x64x64 mini-GEMM per (b,h,chunk))
__global__ __launch_bounds__(256) void ycorr_kernel(
    const float* __restrict__ xbc, const float* __restrict__ cumA,
    const float* __restrict__ Hinit, float* __restrict__ y) {
    int blk = blockIdx.x;            // (b*NHEADS+h)*NCHUNK + c
    int c = blk % NCHUNK;
    int bh = blk / NCHUNK;
    int h = bh % NHEADS, b = bh / NHEADS;
    __shared__ float Cd[LC][D_STATE + 1];
    __shared__ float Hs[HEADDIM][D_STATE + 1];
    int tid = threadIdx.x;
    size_t cbase = (size_t)blk * LC;
    size_t hbase = (size_t)blk * (HEADDIM * D_STATE);
#pragma unroll
    for (int k = 0; k < 16; k++) {
        int idx = tid + k * 256;
        int r = idx >> 6, n = idx & 63;
        size_t row = (size_t)(b * SEQ + c * LC + r);
        Cd[r][n] = xbc[row * CONV_DIM + D_INNER + D_STATE + n] * cumA[cbase + r];
        Hs[r][n] = Hinit[hbase + idx];
    }
    __syncthreads();
    int tx = tid & 15, ty = tid >> 4;   // tx -> p-tile, ty -> t-tile
    float acc[4][4] = {};
    for (int n = 0; n < D_STATE; n++) {
        float cv[4], hv[4];
#pragma unroll
        for (int i = 0; i < 4; i++) cv[i] = Cd[ty * 4 + i][n];
#pragma unroll
        for (int j = 0; j < 4; j++) hv[j] = Hs[tx * 4 + j][n];
#pragma unroll
        for (int i = 0; i < 4; i++)
#pragma unroll
            for (int j = 0; j < 4; j++)
                acc[i][j] = fmaf(cv[i], hv[j], acc[i][j]);
    }
#pragma unroll
    for (int i = 0; i < 4; i++) {
        int t = ty * 4 + i;
        size_t row = (size_t)(b * SEQ + c * LC + t);
#pragma unroll
        for (int j = 0; j < 4; j++) {
            int p = tx * 4 + j;
            size_t oidx = row * D_INNER + h * HEADDIM + p;
            y[oidx] += acc[i][j];
        }
    }
}

// ---------------- gated rmsnorm (in place on y) ----------------
__global__ __launch_bounds__(256) void gatenorm_kernel(
    float* __restrict__ y, const float* __restrict__ zx,
    const float* __restrict__ w) {
    int row = blockIdx.x;
    const float* z = zx + (size_t)row * D_IN_PROJ;
    float* yr = y + (size_t)row * D_INNER;
    float g[6];
    float ss = 0.f;
#pragma unroll
    for (int e = 0; e < 6; e++) {
        int idx = threadIdx.x + e * 256;
        float zv = z[idx];
        float gv = yr[idx] * (zv * sigmoidf_(zv));
        g[e] = gv;
        ss += gv * gv;
    }
    ss = blockReduceSum<4>(ss);
    float sc = rsqrtf(ss * (1.f / D_INNER) + 1e-6f);
#pragma unroll
    for (int e = 0; e < 6; e++) {
        int idx = threadIdx.x + e * 256;
        yr[idx] = g[e] * sc * w[idx];
    }
}

// ---------------- launch ----------------
extern "C" void kernel_launch(void* const* d_in, const int* in_sizes, int n_in,
                              void* d_out, int out_size, void* d_ws, size_t ws_size,
                              hipStream_t stream) {
    const float* x        = (const float*)d_in[0];
    const float* x_prompt = (const float*)d_in[1];
    const float* in_base  = (const float*)d_in[2];
    const float* lA_in    = (const float*)d_in[3];
    const float* lB_in    = (const float*)d_in[4];
    const float* conv_w   = (const float*)d_in[5];
    const float* conv_b   = (const float*)d_in[6];
    const float* dt_bias  = (const float*)d_in[7];
    const float* A_log    = (const float*)d_in[8];
    const float* D_param  = (const float*)d_in[9];
    const float* gnw      = (const float*)d_in[10];
    const float* out_base = (const float*)d_in[11];
    const float* lA_out   = (const float*)d_in[12];
    const float* lB_out   = (const float*)d_in[13];
    const float* loop_nw  = (const float*)d_in[14];
    const float* gate     = (const float*)d_in[15];
    float* out = (float*)d_out;

    float* ws = (float*)d_ws;
    float* W_in  = ws;
    float* W_out = W_in  + (size_t)D_IN_PROJ * D_MODEL;
    float* hbuf  = W_out + (size_t)D_MODEL * D_INNER;
    float* zx    = hbuf  + (size_t)NROWS * D_MODEL;
    float* xbc   = zx    + (size_t)NROWS * D_IN_PROJ;
    float* dtb   = xbc   + (size_t)NROWS * CONV_DIM;
    float* dAb   = dtb   + (size_t)NROWS * NHEADS;
    float* ybuf  = dAb   + (size_t)NROWS * NHEADS;
    float* Fbuf  = ybuf  + (size_t)NROWS * D_INNER;                    // 768*4096
    float* Hinit = Fbuf  + (size_t)BSZ * NHEADS * NCHUNK * HEADDIM * D_STATE;
    float* cumA  = Hinit + (size_t)BSZ * NHEADS * NCHUNK * HEADDIM * D_STATE; // 768*64

    build_w_in_kernel<<<(D_IN_PROJ * D_MODEL + 255) / 256, 256, 0, stream>>>(in_base, lA_in, lB_in, W_in);
    build_w_out_kernel<<<(D_MODEL * D_INNER + 255) / 256, 256, 0, stream>>>(out_base, lA_out, lB_out, W_out);

    for (int i = 0; i < 2; i++) {   // n_loops = 2 (fixed by setup_inputs)
        const float* xsrc = (i == 0) ? x : out;
        rmsrope_kernel<<<NROWS, 384, 0, stream>>>(xsrc, loop_nw, hbuf, i);

        dim3 g1((D_IN_PROJ + BN - 1) / BN, NROWS / BM);
        gemm_nt_kernel<<<g1, 256, 0, stream>>>(hbuf, W_in, zx, NROWS, D_IN_PROJ, D_MODEL,
                                               nullptr, nullptr);

        dt_kernel<<<(NROWS * NHEADS + 255) / 256, 256, 0, stream>>>(zx, dt_bias, A_log, dtb, dAb);
        conv_kernel<<<(BSZ * SEQ * CONV_DIM + 255) / 256, 256, 0, stream>>>(zx, conv_w, conv_b, xbc);

        cuma_kernel<<<(BSZ * NHEADS * NCHUNK + 255) / 256, 256, 0, stream>>>(dAb, cumA);
        scan_chunk_kernel<<<BSZ * NHEADS * NCHUNK * 16, 256, 0, stream>>>(xbc, dtb, dAb, D_param, ybuf, Fbuf);
        combine_kernel<<<BSZ * NHEADS, 256, 0, stream>>>(Fbuf, cumA, Hinit);
        ycorr_kernel<<<BSZ * NHEADS * NCHUNK, 256, 0, stream>>>(xbc, cumA, Hinit, ybuf);

        gatenorm_kernel<<<NROWS, 256, 0, stream>>>(ybuf, zx, gnw);

        dim3 g2(D_MODEL / BN, NROWS / BM);
        gemm_nt_kernel<<<g2, 256, 0, stream>>>(ybuf, W_out, out, NROWS, D_MODEL, D_INNER,
                                               x_prompt, gate);
    }
}

// Round 4
// 837.492 us; speedup vs baseline: 2.3140x; 1.7268x over previous
//
#include <hip/hip_runtime.h>
#include <hip/hip_bf16.h>
#include <math.h>

#define D_MODEL 768
#define D_STATE 64
#define D_CONV 4
#define D_INNER 1536
#define HEADDIM 64
#define NHEADS 24
#define RANK 8
#define D_IN_PROJ 3224   // 2*1536 + 2*64 + 24
#define NPAD 3328        // D_IN_PROJ padded to multiple of 128
#define ZSTR 3328        // zx row stride (padded)
#define CONV_DIM 1664    // 1536 + 128
#define BSZ 2
#define SEQ 1024
#define NROWS (BSZ*SEQ)  // 2048
#define SCALE_LORA 2.0f  // 16/8
#define LC 64            // chunk length
#define NCHUNK (SEQ/LC)  // 16

typedef __attribute__((ext_vector_type(8))) short bf16x8;
typedef __attribute__((ext_vector_type(4))) float f32x4;

// ---------------- helpers ----------------

__device__ inline float waveReduceSum(float v) {
#pragma unroll
    for (int m = 32; m; m >>= 1) v += __shfl_xor(v, m, 64);
    return v;
}

template <int NWAVES>
__device__ inline float blockReduceSum(float v) {
    __shared__ float tmp[NWAVES];
    int lane = threadIdx.x & 63, wid = threadIdx.x >> 6;
    v = waveReduceSum(v);
    if (lane == 0) tmp[wid] = v;
    __syncthreads();
    float tot = 0.f;
#pragma unroll
    for (int i = 0; i < NWAVES; i++) tot += tmp[i];
    return tot;
}

__device__ inline float sigmoidf_(float x) { return 1.f / (1.f + expf(-x)); }

// float -> bf16 (round-to-nearest-even)
__device__ inline unsigned short f2bf(float f) {
    union { float f; unsigned int u; } v; v.f = f;
    unsigned int r = (v.u + 0x7fffu + ((v.u >> 16) & 1u)) >> 16;
    return (unsigned short)r;
}

__device__ inline void load_lds16(const void* g, void* l) {
    __builtin_amdgcn_global_load_lds((const __attribute__((address_space(1))) void*)g,
                                     (__attribute__((address_space(3))) void*)l, 16, 0, 0);
}

// ---------------- weight build (f32 base + LoRA -> bf16) ----------------

__global__ void build_w_in_kernel(const float* __restrict__ base,
                                  const float* __restrict__ lA,   // [RANK][D_MODEL]
                                  const float* __restrict__ lB,   // [D_IN_PROJ][RANK]
                                  unsigned short* __restrict__ W) {  // [NPAD][D_MODEL] bf16
    int idx = blockIdx.x * blockDim.x + threadIdx.x;
    if (idx >= NPAD * D_MODEL) return;
    int r = idx / D_MODEL, c = idx - r * D_MODEL;
    if (r >= D_IN_PROJ) { W[idx] = 0; return; }
    float s = 0.f;
#pragma unroll
    for (int k = 0; k < RANK; k++) s += lB[r * RANK + k] * lA[k * D_MODEL + c];
    W[idx] = f2bf(base[(size_t)r * D_MODEL + c] + SCALE_LORA * s);
}

__global__ void build_w_out_kernel(const float* __restrict__ base,
                                   const float* __restrict__ lA,   // [RANK][D_INNER]
                                   const float* __restrict__ lB,   // [D_MODEL][RANK]
                                   unsigned short* __restrict__ W) { // [D_MODEL][D_INNER] bf16
    int idx = blockIdx.x * blockDim.x + threadIdx.x;
    if (idx >= D_MODEL * D_INNER) return;
    int r = idx / D_INNER, c = idx - r * D_INNER;
    float s = 0.f;
#pragma unroll
    for (int k = 0; k < RANK; k++) s += lB[r * RANK + k] * lA[k * D_INNER + c];
    W[idx] = f2bf(base[idx] + SCALE_LORA * s);
}

// ---------------- rmsnorm + rope -> bf16 ----------------
__global__ __launch_bounds__(384) void rmsrope_kernel(
    const float* __restrict__ x, const float* __restrict__ w,
    unsigned short* __restrict__ out, int loop_i) {
    int row = blockIdx.x;
    const float* xr = x + (size_t)row * D_MODEL;
    int j = threadIdx.x;
    float x0 = xr[2 * j], x1 = xr[2 * j + 1];
    float ss = blockReduceSum<6>(x0 * x0 + x1 * x1);
    float sc = rsqrtf(ss * (1.f / D_MODEL) + 1e-6f);
    float y0 = x0 * sc * w[2 * j];
    float y1 = x1 * sc * w[2 * j + 1];
    float ang = (float)loop_i * expf((float)(2 * j) * (-9.210340371976184f / (float)D_MODEL));
    float c = cosf(ang), sn = sinf(ang);
    unsigned short* orow = out + (size_t)row * D_MODEL;
    orow[2 * j]     = f2bf(y0 * c - y1 * sn);
    orow[2 * j + 1] = f2bf(y1 * c + y0 * sn);
}

// ---------------- bf16 MFMA GEMM: C[M][Cstride] = A[M][K] . B[N][K]^T ----------------
// 128x128 tile, BK=64, 256 threads = 4 waves (2x2), 4x4 16x16x32 fragments per wave.
// If gate != nullptr: C += gate[n]*xp[m*Cstride+n]
__global__ __launch_bounds__(256) void gemm_bf16_kernel(
    const unsigned short* __restrict__ A,   // [M][K] bf16
    const unsigned short* __restrict__ B,   // [N][K] bf16
    float* __restrict__ C, int M, int N, int K, int Cstride,
    const float* __restrict__ xp, const float* __restrict__ gate) {
    __shared__ unsigned short lsA[128 * 64];
    __shared__ unsigned short lsB[128 * 64];
    int t = threadIdx.x;
    int w = t >> 6, lane = t & 63;
    int n0 = blockIdx.x * 128, m0 = blockIdx.y * 128;
    int wr = w >> 1, wc = w & 1;
    f32x4 acc[4][4];
#pragma unroll
    for (int i = 0; i < 4; i++)
#pragma unroll
        for (int j = 0; j < 4; j++) acc[i][j] = (f32x4){0.f, 0.f, 0.f, 0.f};

    for (int k0 = 0; k0 < K; k0 += 64) {
        __syncthreads();   // all waves done reading previous tile
#pragma unroll
        for (int o = 0; o < 4; o++) {
            int s = o * 256 + t;
            int row = s >> 3, colE = (s & 7) << 3;
            const unsigned short* ga = &A[(size_t)(m0 + row) * K + k0 + colE];
            const unsigned short* gb = &B[(size_t)(n0 + row) * K + k0 + colE];
            unsigned short* la = &lsA[(size_t)(o * 256 + (t & ~63)) * 8];
            unsigned short* lb = &lsB[(size_t)(o * 256 + (t & ~63)) * 8];
            load_lds16(ga, la);
            load_lds16(gb, lb);
        }
        __syncthreads();   // staging complete (compiler drains vmcnt before barrier)
#pragma unroll
        for (int kk = 0; kk < 2; kk++) {
            bf16x8 af[4], bfr[4];
            int kof = kk * 32 + (lane >> 4) * 8;
#pragma unroll
            for (int i = 0; i < 4; i++) {
                int row = wr * 64 + i * 16 + (lane & 15);
                af[i] = *(const bf16x8*)&lsA[row * 64 + kof];
            }
#pragma unroll
            for (int j = 0; j < 4; j++) {
                int row = wc * 64 + j * 16 + (lane & 15);
                bfr[j] = *(const bf16x8*)&lsB[row * 64 + kof];
            }
#pragma unroll
            for (int i = 0; i < 4; i++)
#pragma unroll
                for (int j = 0; j < 4; j++)
                    acc[i][j] = __builtin_amdgcn_mfma_f32_16x16x32_bf16(af[i], bfr[j], acc[i][j], 0, 0, 0);
        }
    }
#pragma unroll
    for (int i = 0; i < 4; i++) {
#pragma unroll
        for (int j = 0; j < 4; j++) {
#pragma unroll
            for (int r = 0; r < 4; r++) {
                int row = m0 + wr * 64 + i * 16 + (lane >> 4) * 4 + r;
                int col = n0 + wc * 64 + j * 16 + (lane & 15);
                float v = acc[i][j][r];
                if (gate) v += gate[col] * xp[(size_t)row * Cstride + col];
                C[(size_t)row * Cstride + col] = v;
            }
        }
    }
}

// ---------------- dt / dA ----------------
__global__ void dt_kernel(const float* __restrict__ zx, const float* __restrict__ dt_bias,
                          const float* __restrict__ A_log,
                          float* __restrict__ dtb, float* __restrict__ dAb) {
    int idx = blockIdx.x * blockDim.x + threadIdx.x;
    if (idx >= NROWS * NHEADS) return;
    int row = idx / NHEADS, h = idx - row * NHEADS;
    float raw = zx[(size_t)row * ZSTR + (D_INNER + CONV_DIM) + h] + dt_bias[h];
    float dt = raw > 20.f ? raw : log1pf(expf(raw));
    float A = -expf(A_log[h]);
    dtb[idx] = dt;
    dAb[idx] = expf(dt * A);
}

// ---------------- depthwise causal conv + silu ----------------
__global__ void conv_kernel(const float* __restrict__ zx, const float* __restrict__ cw,
                            const float* __restrict__ cb, float* __restrict__ xbc) {
    int idx = blockIdx.x * blockDim.x + threadIdx.x;
    if (idx >= BSZ * SEQ * CONV_DIM) return;
    int c = idx % CONV_DIM;
    int l = (idx / CONV_DIM) % SEQ;
    int b = idx / (CONV_DIM * SEQ);
    const float* base = zx + (size_t)b * SEQ * ZSTR + D_INNER + c;
    float acc = cb[c];
#pragma unroll
    for (int t = 0; t < 4; t++) {
        int ll = l - 3 + t;
        if (ll >= 0) acc = fmaf(cw[c * 4 + t], base[(size_t)ll * ZSTR], acc);
    }
    xbc[idx] = acc * sigmoidf_(acc);
}

// ---------------- chunked SSM scan ----------------
__global__ void cuma_kernel(const float* __restrict__ dAb, float* __restrict__ cumA) {
    int id = blockIdx.x * blockDim.x + threadIdx.x;
    if (id >= BSZ * NHEADS * NCHUNK) return;
    int c = id % NCHUNK;
    int bh = id / NCHUNK;
    int h = bh % NHEADS, b = bh / NHEADS;
    float r = 1.f;
    for (int t = 0; t < LC; t++) {
        size_t row = (size_t)(b * SEQ + c * LC + t);
        r *= dAb[row * NHEADS + h];
        cumA[(size_t)id * LC + t] = r;
    }
}

__global__ __launch_bounds__(256) void scan_chunk_kernel(
    const float* __restrict__ xbc,
    const float* __restrict__ dtb,
    const float* __restrict__ dAb,
    const float* __restrict__ Dp,
    float* __restrict__ y,
    float* __restrict__ Fbuf) {
    int blk = blockIdx.x;
    int pg = blk & 15;
    int c  = (blk >> 4) & (NCHUNK - 1);
    int bh = blk >> 8;
    int h = bh % NHEADS;
    int b = bh / NHEADS;
    int lane = threadIdx.x & 63;
    int p = pg * 4 + (threadIdx.x >> 6);
    float D_h = Dp[h];
    float s = 0.f;
    const int xcol = h * HEADDIM + p;
    const int t0 = c * LC;
    for (int t = 0; t < LC; t++) {
        size_t row = (size_t)(b * SEQ + t0 + t);
        const float* xr = xbc + row * CONV_DIM;
        float dA = dAb[row * NHEADS + h];
        float dt = dtb[row * NHEADS + h];
        float Bv = xr[D_INNER + lane];
        float Cv = xr[D_INNER + D_STATE + lane];
        float xv = xr[xcol];
        s = fmaf(dA, s, dt * xv * Bv);
        float yp = Cv * s;
#pragma unroll
        for (int m = 1; m < 64; m <<= 1) yp += __shfl_xor(yp, m, 64);
        if (lane == 0) y[row * D_INNER + xcol] = fmaf(D_h, xv, yp);
    }
    Fbuf[((size_t)(bh * NCHUNK + c) * HEADDIM + p) * D_STATE + lane] = s;
}

__global__ __launch_bounds__(256) void combine_kernel(
    const float* __restrict__ Fbuf, const float* __restrict__ cumA,
    float* __restrict__ Hinit) {
    int bh = blockIdx.x;
    int tid = threadIdx.x;
    float H[16];
#pragma unroll
    for (int k = 0; k < 16; k++) H[k] = 0.f;
    for (int c = 0; c < NCHUNK; c++) {
        size_t base = (size_t)(bh * NCHUNK + c) * (HEADDIM * D_STATE);
        float pA = cumA[(size_t)(bh * NCHUNK + c) * LC + (LC - 1)];
#pragma unroll
        for (int k = 0; k < 16; k++) {
            size_t idx = base + tid + k * 256;
            Hinit[idx] = H[k];
            H[k] = fmaf(pA, H[k], Fbuf[idx]);
        }
    }
}

__global__ __launch_bounds__(256) void ycorr_kernel(
    const float* __restrict__ xbc, const float* __restrict__ cumA,
    const float* __restrict__ Hinit, float* __restrict__ y) {
    int blk = blockIdx.x;
    int c = blk % NCHUNK;
    int bh = blk / NCHUNK;
    int h = bh % NHEADS, b = bh / NHEADS;
    __shared__ float Cd[LC][D_STATE + 1];
    __shared__ float Hs[HEADDIM][D_STATE + 1];
    int tid = threadIdx.x;
    size_t cbase = (size_t)blk * LC;
    size_t hbase = (size_t)blk * (HEADDIM * D_STATE);
#pragma unroll
    for (int k = 0; k < 16; k++) {
        int idx = tid + k * 256;
        int r = idx >> 6, n = idx & 63;
        size_t row = (size_t)(b * SEQ + c * LC + r);
        Cd[r][n] = xbc[row * CONV_DIM + D_INNER + D_STATE + n] * cumA[cbase + r];
        Hs[r][n] = Hinit[hbase + idx];
    }
    __syncthreads();
    int tx = tid & 15, ty = tid >> 4;
    float acc[4][4] = {};
    for (int n = 0; n < D_STATE; n++) {
        float cv[4], hv[4];
#pragma unroll
        for (int i = 0; i < 4; i++) cv[i] = Cd[ty * 4 + i][n];
#pragma unroll
        for (int j = 0; j < 4; j++) hv[j] = Hs[tx * 4 + j][n];
#pragma unroll
        for (int i = 0; i < 4; i++)
#pragma unroll
            for (int j = 0; j < 4; j++)
                acc[i][j] = fmaf(cv[i], hv[j], acc[i][j]);
    }
#pragma unroll
    for (int i = 0; i < 4; i++) {
        int tt = ty * 4 + i;
        size_t row = (size_t)(b * SEQ + c * LC + tt);
#pragma unroll
        for (int j = 0; j < 4; j++) {
            int p = tx * 4 + j;
            size_t oidx = row * D_INNER + h * HEADDIM + p;
            y[oidx] += acc[i][j];
        }
    }
}

// ---------------- gated rmsnorm -> bf16 ----------------
__global__ __launch_bounds__(256) void gatenorm_kernel(
    const float* __restrict__ y, const float* __restrict__ zx,
    const float* __restrict__ w, unsigned short* __restrict__ out) {
    int row = blockIdx.x;
    const float* z = zx + (size_t)row * ZSTR;
    const float* yr = y + (size_t)row * D_INNER;
    float g[6];
    float ss = 0.f;
#pragma unroll
    for (int e = 0; e < 6; e++) {
        int idx = threadIdx.x + e * 256;
        float zv = z[idx];
        float gv = yr[idx] * (zv * sigmoidf_(zv));
        g[e] = gv;
        ss += gv * gv;
    }
    ss = blockReduceSum<4>(ss);
    float sc = rsqrtf(ss * (1.f / D_INNER) + 1e-6f);
#pragma unroll
    for (int e = 0; e < 6; e++) {
        int idx = threadIdx.x + e * 256;
        out[(size_t)row * D_INNER + idx] = f2bf(g[e] * sc * w[idx]);
    }
}

// ---------------- launch ----------------
extern "C" void kernel_launch(void* const* d_in, const int* in_sizes, int n_in,
                              void* d_out, int out_size, void* d_ws, size_t ws_size,
                              hipStream_t stream) {
    const float* x        = (const float*)d_in[0];
    const float* x_prompt = (const float*)d_in[1];
    const float* in_base  = (const float*)d_in[2];
    const float* lA_in    = (const float*)d_in[3];
    const float* lB_in    = (const float*)d_in[4];
    const float* conv_w   = (const float*)d_in[5];
    const float* conv_b   = (const float*)d_in[6];
    const float* dt_bias  = (const float*)d_in[7];
    const float* A_log    = (const float*)d_in[8];
    const float* D_param  = (const float*)d_in[9];
    const float* gnw      = (const float*)d_in[10];
    const float* out_base = (const float*)d_in[11];
    const float* lA_out   = (const float*)d_in[12];
    const float* lB_out   = (const float*)d_in[13];
    const float* loop_nw  = (const float*)d_in[14];
    const float* gate     = (const float*)d_in[15];
    float* out = (float*)d_out;

    float* ws_f = (float*)d_ws;
    float* zx    = ws_f;                                   // 2048*3328 f32
    float* xbc   = zx    + (size_t)NROWS * ZSTR;           // 2048*1664
    float* dtb   = xbc   + (size_t)NROWS * CONV_DIM;       // 2048*24
    float* dAb   = dtb   + (size_t)NROWS * NHEADS;
    float* ybuf  = dAb   + (size_t)NROWS * NHEADS;         // 2048*1536
    float* Fbuf  = ybuf  + (size_t)NROWS * D_INNER;        // 48*16*4096
    float* Hinit = Fbuf  + (size_t)BSZ * NHEADS * NCHUNK * HEADDIM * D_STATE;
    float* cumA  = Hinit + (size_t)BSZ * NHEADS * NCHUNK * HEADDIM * D_STATE; // 48*16*64
    unsigned short* W_in  = (unsigned short*)(cumA + (size_t)BSZ * NHEADS * NCHUNK * LC);
    unsigned short* W_out = W_in  + (size_t)NPAD * D_MODEL;
    unsigned short* hbuf  = W_out + (size_t)D_MODEL * D_INNER;
    unsigned short* ygt   = hbuf  + (size_t)NROWS * D_MODEL;

    build_w_in_kernel<<<(NPAD * D_MODEL + 255) / 256, 256, 0, stream>>>(in_base, lA_in, lB_in, W_in);
    build_w_out_kernel<<<(D_MODEL * D_INNER + 255) / 256, 256, 0, stream>>>(out_base, lA_out, lB_out, W_out);

    for (int i = 0; i < 2; i++) {   // n_loops = 2 (fixed by setup_inputs)
        const float* xsrc = (i == 0) ? x : out;
        rmsrope_kernel<<<NROWS, 384, 0, stream>>>(xsrc, loop_nw, hbuf, i);

        dim3 g1(NPAD / 128, NROWS / 128);
        gemm_bf16_kernel<<<g1, 256, 0, stream>>>(hbuf, W_in, zx, NROWS, NPAD, D_MODEL, ZSTR,
                                                 nullptr, nullptr);

        dt_kernel<<<(NROWS * NHEADS + 255) / 256, 256, 0, stream>>>(zx, dt_bias, A_log, dtb, dAb);
        conv_kernel<<<(BSZ * SEQ * CONV_DIM + 255) / 256, 256, 0, stream>>>(zx, conv_w, conv_b, xbc);

        cuma_kernel<<<(BSZ * NHEADS * NCHUNK + 255) / 256, 256, 0, stream>>>(dAb, cumA);
        scan_chunk_kernel<<<BSZ * NHEADS * NCHUNK * 16, 256, 0, stream>>>(xbc, dtb, dAb, D_param, ybuf, Fbuf);
        combine_kernel<<<BSZ * NHEADS, 256, 0, stream>>>(Fbuf, cumA, Hinit);
        ycorr_kernel<<<BSZ * NHEADS * NCHUNK, 256, 0, stream>>>(xbc, cumA, Hinit, ybuf);

        gatenorm_kernel<<<NROWS, 256, 0, stream>>>(ybuf, zx, gnw, ygt);

        dim3 g2(D_MODEL / 128, NROWS / 128);
        gemm_bf16_kernel<<<g2, 256, 0, stream>>>(ygt, W_out, out, NROWS, D_MODEL, D_INNER, D_MODEL,
                                                 x_prompt, gate);
    }
}

// Round 5
// 384.840 us; speedup vs baseline: 5.0357x; 2.1762x over previous
//
#include <hip/hip_runtime.h>
#include <hip/hip_bf16.h>
#include <math.h>

#define D_MODEL 768
#define D_STATE 64
#define D_CONV 4
#define D_INNER 1536
#define HEADDIM 64
#define NHEADS 24
#define RANK 8
#define D_IN_PROJ 3224   // 2*1536 + 2*64 + 24
#define NPAD 3328        // D_IN_PROJ padded to multiple of 128
#define ZSTR 3328        // zx row stride (padded)
#define CONV_DIM 1664    // 1536 + 128
#define BSZ 2
#define SEQ 1024
#define NROWS (BSZ*SEQ)  // 2048
#define SCALE_LORA 2.0f  // 16/8
#define LC 64            // chunk length
#define NCHUNK (SEQ/LC)  // 16
#define LSTR 72          // LDS row stride (bf16 elems): 144B, 16-aligned, 4p%32 banks

typedef __attribute__((ext_vector_type(8))) short bf16x8;
typedef __attribute__((ext_vector_type(4))) float f32x4;

// ---------------- helpers ----------------

__device__ inline float waveReduceSum(float v) {
#pragma unroll
    for (int m = 32; m; m >>= 1) v += __shfl_xor(v, m, 64);
    return v;
}

template <int NWAVES>
__device__ inline float blockReduceSum(float v) {
    __shared__ float tmp[NWAVES];
    int lane = threadIdx.x & 63, wid = threadIdx.x >> 6;
    v = waveReduceSum(v);
    if (lane == 0) tmp[wid] = v;
    __syncthreads();
    float tot = 0.f;
#pragma unroll
    for (int i = 0; i < NWAVES; i++) tot += tmp[i];
    return tot;
}

__device__ inline float sigmoidf_(float x) { return 1.f / (1.f + expf(-x)); }

// float -> bf16 (round-to-nearest-even)
__device__ inline unsigned short f2bf(float f) {
    union { float f; unsigned int u; } v; v.f = f;
    unsigned int r = (v.u + 0x7fffu + ((v.u >> 16) & 1u)) >> 16;
    return (unsigned short)r;
}

__device__ inline void load_lds16(const void* g, void* l) {
    __builtin_amdgcn_global_load_lds((const __attribute__((address_space(1))) void*)g,
                                     (__attribute__((address_space(3))) void*)l, 16, 0, 0);
}

// ---------------- weight build (f32 base + LoRA -> bf16) ----------------

__global__ void build_w_in_kernel(const float* __restrict__ base,
                                  const float* __restrict__ lA,
                                  const float* __restrict__ lB,
                                  unsigned short* __restrict__ W) {  // [NPAD][D_MODEL]
    int idx = blockIdx.x * blockDim.x + threadIdx.x;
    if (idx >= NPAD * D_MODEL) return;
    int r = idx / D_MODEL, c = idx - r * D_MODEL;
    if (r >= D_IN_PROJ) { W[idx] = 0; return; }
    float s = 0.f;
#pragma unroll
    for (int k = 0; k < RANK; k++) s += lB[r * RANK + k] * lA[k * D_MODEL + c];
    W[idx] = f2bf(base[(size_t)r * D_MODEL + c] + SCALE_LORA * s);
}

__global__ void build_w_out_kernel(const float* __restrict__ base,
                                   const float* __restrict__ lA,
                                   const float* __restrict__ lB,
                                   unsigned short* __restrict__ W) { // [D_MODEL][D_INNER]
    int idx = blockIdx.x * blockDim.x + threadIdx.x;
    if (idx >= D_MODEL * D_INNER) return;
    int r = idx / D_INNER, c = idx - r * D_INNER;
    float s = 0.f;
#pragma unroll
    for (int k = 0; k < RANK; k++) s += lB[r * RANK + k] * lA[k * D_INNER + c];
    W[idx] = f2bf(base[idx] + SCALE_LORA * s);
}

// ---------------- rmsnorm + rope -> bf16 ----------------
__global__ __launch_bounds__(384) void rmsrope_kernel(
    const float* __restrict__ x, const float* __restrict__ w,
    unsigned short* __restrict__ out, int loop_i) {
    int row = blockIdx.x;
    const float* xr = x + (size_t)row * D_MODEL;
    int j = threadIdx.x;
    float x0 = xr[2 * j], x1 = xr[2 * j + 1];
    float ss = blockReduceSum<6>(x0 * x0 + x1 * x1);
    float sc = rsqrtf(ss * (1.f / D_MODEL) + 1e-6f);
    float y0 = x0 * sc * w[2 * j];
    float y1 = x1 * sc * w[2 * j + 1];
    float ang = (float)loop_i * expf((float)(2 * j) * (-9.210340371976184f / (float)D_MODEL));
    float c = cosf(ang), sn = sinf(ang);
    unsigned short* orow = out + (size_t)row * D_MODEL;
    orow[2 * j]     = f2bf(y0 * c - y1 * sn);
    orow[2 * j + 1] = f2bf(y1 * c + y0 * sn);
}

// ---------------- bf16 MFMA GEMM (128x128 tile, BK=64) ----------------
__global__ __launch_bounds__(256) void gemm_bf16_kernel(
    const unsigned short* __restrict__ A,
    const unsigned short* __restrict__ B,
    float* __restrict__ C, int M, int N, int K, int Cstride,
    const float* __restrict__ xp, const float* __restrict__ gate) {
    __shared__ unsigned short lsA[128 * 64];
    __shared__ unsigned short lsB[128 * 64];
    int t = threadIdx.x;
    int w = t >> 6, lane = t & 63;
    int n0 = blockIdx.x * 128, m0 = blockIdx.y * 128;
    int wr = w >> 1, wc = w & 1;
    f32x4 acc[4][4];
#pragma unroll
    for (int i = 0; i < 4; i++)
#pragma unroll
        for (int j = 0; j < 4; j++) acc[i][j] = (f32x4){0.f, 0.f, 0.f, 0.f};

    for (int k0 = 0; k0 < K; k0 += 64) {
        __syncthreads();
#pragma unroll
        for (int o = 0; o < 4; o++) {
            int s = o * 256 + t;
            int row = s >> 3, colE = (s & 7) << 3;
            const unsigned short* ga = &A[(size_t)(m0 + row) * K + k0 + colE];
            const unsigned short* gb = &B[(size_t)(n0 + row) * K + k0 + colE];
            unsigned short* la = &lsA[(size_t)(o * 256 + (t & ~63)) * 8];
            unsigned short* lb = &lsB[(size_t)(o * 256 + (t & ~63)) * 8];
            load_lds16(ga, la);
            load_lds16(gb, lb);
        }
        __syncthreads();
#pragma unroll
        for (int kk = 0; kk < 2; kk++) {
            bf16x8 af[4], bfr[4];
            int kof = kk * 32 + (lane >> 4) * 8;
#pragma unroll
            for (int i = 0; i < 4; i++) {
                int row = wr * 64 + i * 16 + (lane & 15);
                af[i] = *(const bf16x8*)&lsA[row * 64 + kof];
            }
#pragma unroll
            for (int j = 0; j < 4; j++) {
                int row = wc * 64 + j * 16 + (lane & 15);
                bfr[j] = *(const bf16x8*)&lsB[row * 64 + kof];
            }
#pragma unroll
            for (int i = 0; i < 4; i++)
#pragma unroll
                for (int j = 0; j < 4; j++)
                    acc[i][j] = __builtin_amdgcn_mfma_f32_16x16x32_bf16(af[i], bfr[j], acc[i][j], 0, 0, 0);
        }
    }
#pragma unroll
    for (int i = 0; i < 4; i++) {
#pragma unroll
        for (int j = 0; j < 4; j++) {
#pragma unroll
            for (int r = 0; r < 4; r++) {
                int row = m0 + wr * 64 + i * 16 + (lane >> 4) * 4 + r;
                int col = n0 + wc * 64 + j * 16 + (lane & 15);
                float v = acc[i][j][r];
                if (gate) v += gate[col] * xp[(size_t)row * Cstride + col];
                C[(size_t)row * Cstride + col] = v;
            }
        }
    }
}

// ---------------- depthwise causal conv + silu ----------------
__global__ void conv_kernel(const float* __restrict__ zx, const float* __restrict__ cw,
                            const float* __restrict__ cb, float* __restrict__ xbc) {
    int idx = blockIdx.x * blockDim.x + threadIdx.x;
    if (idx >= BSZ * SEQ * CONV_DIM) return;
    int c = idx % CONV_DIM;
    int l = (idx / CONV_DIM) % SEQ;
    int b = idx / (CONV_DIM * SEQ);
    const float* base = zx + (size_t)b * SEQ * ZSTR + D_INNER + c;
    float acc = cb[c];
#pragma unroll
    for (int t = 0; t < 4; t++) {
        int ll = l - 3 + t;
        if (ll >= 0) acc = fmaf(cw[c * 4 + t], base[(size_t)ll * ZSTR], acc);
    }
    xbc[idx] = acc * sigmoidf_(acc);
}

// ---------------- MFMA chunked scan ----------------
// One block per (b,h,chunk) = 768 blocks. 256 threads = 4 waves.
// Computes intra-chunk Y (incl. D*x), chunk-final state F[n][p], cumA[t]=exp(s_t).
__global__ __launch_bounds__(256) void scan_mfma_kernel(
    const float* __restrict__ xbc,   // [NROWS][CONV_DIM]
    const float* __restrict__ zx,    // [NROWS][ZSTR] (dt raw at col 3200+h)
    const float* __restrict__ dt_bias,
    const float* __restrict__ A_log,
    const float* __restrict__ Dp,
    float* __restrict__ y,           // [NROWS][D_INNER]
    float* __restrict__ Fbuf,        // [blk][n][p]
    float* __restrict__ cumA) {      // [blk][LC]
    __shared__ unsigned short Cc[64][LSTR];
    __shared__ unsigned short Bb[64][LSTR];
    __shared__ unsigned short Xt[64][LSTR];   // Xt[p][u]
    __shared__ unsigned short Bw[64][LSTR];   // Bw[n][u] (weighted B^T)
    __shared__ unsigned short Mm[64][LSTR];
    __shared__ float s_lds[64];
    __shared__ float dt_lds[64];

    int blk = blockIdx.x;
    int c = blk % NCHUNK;
    int bh = blk / NCHUNK;
    int h = bh % NHEADS, b = bh / NHEADS;
    int tid = threadIdx.x;
    int w = tid >> 6, lane = tid & 63;
    const int t0 = c * LC;

    // wave 0: dt softplus + log-decay prefix + cumA
    if (w == 0) {
        int t = lane;
        size_t row = (size_t)(b * SEQ + t0 + t);
        float raw = zx[row * ZSTR + (D_INNER + CONV_DIM) + h] + dt_bias[h];
        float dt_t = raw > 20.f ? raw : log1pf(expf(raw));
        float s = dt_t * (-expf(A_log[h]));
#pragma unroll
        for (int off = 1; off < 64; off <<= 1) {
            float v = __shfl_up(s, off, 64);
            if (lane >= off) s += v;
        }
        s_lds[t] = s;
        dt_lds[t] = dt_t;
        cumA[(size_t)blk * LC + t] = expf(s);
    }

    // stage C, B (natural) and X (transposed); keep B values in regs for Bw
    float breg[16];
#pragma unroll
    for (int k = 0; k < 16; k++) {
        int idx = k * 256 + tid;
        int r = idx >> 6, ci = idx & 63;
        size_t row = (size_t)(b * SEQ + t0 + r) * CONV_DIM;
        float cv = xbc[row + D_INNER + D_STATE + ci];
        float bv = xbc[row + D_INNER + ci];
        float xv = xbc[row + h * HEADDIM + ci];
        Cc[r][ci] = f2bf(cv);
        Bb[r][ci] = f2bf(bv);
        Xt[ci][r] = f2bf(xv);
        breg[k] = bv;
    }
    __syncthreads();

    // Bw[n][u] = B[u][n] * exp(s63 - s_u) * dt_u (needs s from wave 0)
    float s63 = s_lds[63];
#pragma unroll
    for (int k = 0; k < 16; k++) {
        int idx = k * 256 + tid;
        int r = idx >> 6, ci = idx & 63;     // r = u (wave-uniform per k), ci = n
        float wu = expf(s63 - s_lds[r]) * dt_lds[r];
        Bw[ci][r] = f2bf(breg[k] * wu);
    }

    // G = C . B^T : wave w owns t-rows 16w..16w+15
    f32x4 accG[4];
#pragma unroll
    for (int j = 0; j < 4; j++) accG[j] = (f32x4){0.f, 0.f, 0.f, 0.f};
#pragma unroll
    for (int kk = 0; kk < 2; kk++) {
        int kof = kk * 32 + (lane >> 4) * 8;
        bf16x8 afr = *(const bf16x8*)&Cc[16 * w + (lane & 15)][kof];
#pragma unroll
        for (int j = 0; j < 4; j++) {
            bf16x8 bfr = *(const bf16x8*)&Bb[16 * j + (lane & 15)][kof];
            accG[j] = __builtin_amdgcn_mfma_f32_16x16x32_bf16(afr, bfr, accG[j], 0, 0, 0);
        }
    }
    // mask + decay scale -> Mm (bf16)
#pragma unroll
    for (int j = 0; j < 4; j++) {
#pragma unroll
        for (int r = 0; r < 4; r++) {
            int t = 16 * w + (lane >> 4) * 4 + r;
            int u = 16 * j + (lane & 15);
            float v = 0.f;
            if (u <= t) v = accG[j][r] * dt_lds[u] * expf(s_lds[t] - s_lds[u]);
            Mm[t][u] = f2bf(v);
        }
    }
    __syncthreads();

    // Y = M . X^T  (+ D*x, exact f32 from global)
    f32x4 accY[4];
#pragma unroll
    for (int j = 0; j < 4; j++) accY[j] = (f32x4){0.f, 0.f, 0.f, 0.f};
#pragma unroll
    for (int kk = 0; kk < 2; kk++) {
        int kof = kk * 32 + (lane >> 4) * 8;
        bf16x8 afr = *(const bf16x8*)&Mm[16 * w + (lane & 15)][kof];
#pragma unroll
        for (int j = 0; j < 4; j++) {
            bf16x8 bfr = *(const bf16x8*)&Xt[16 * j + (lane & 15)][kof];
            accY[j] = __builtin_amdgcn_mfma_f32_16x16x32_bf16(afr, bfr, accY[j], 0, 0, 0);
        }
    }
    float D_h = Dp[h];
#pragma unroll
    for (int j = 0; j < 4; j++) {
#pragma unroll
        for (int r = 0; r < 4; r++) {
            int t = 16 * w + (lane >> 4) * 4 + r;
            int p = 16 * j + (lane & 15);
            size_t row = (size_t)(b * SEQ + t0 + t);
            float xv = xbc[row * CONV_DIM + h * HEADDIM + p];
            y[row * D_INNER + h * HEADDIM + p] = accY[j][r] + D_h * xv;
        }
    }

    // F[n][p] = sum_u Bw[n][u] * X[u][p]
    f32x4 accF[4];
#pragma unroll
    for (int j = 0; j < 4; j++) accF[j] = (f32x4){0.f, 0.f, 0.f, 0.f};
#pragma unroll
    for (int kk = 0; kk < 2; kk++) {
        int kof = kk * 32 + (lane >> 4) * 8;
        bf16x8 afr = *(const bf16x8*)&Bw[16 * w + (lane & 15)][kof];
#pragma unroll
        for (int j = 0; j < 4; j++) {
            bf16x8 bfr = *(const bf16x8*)&Xt[16 * j + (lane & 15)][kof];
            accF[j] = __builtin_amdgcn_mfma_f32_16x16x32_bf16(afr, bfr, accF[j], 0, 0, 0);
        }
    }
#pragma unroll
    for (int j = 0; j < 4; j++) {
#pragma unroll
        for (int r = 0; r < 4; r++) {
            int n = 16 * w + (lane >> 4) * 4 + r;
            int p = 16 * j + (lane & 15);
            Fbuf[(size_t)blk * (HEADDIM * D_STATE) + n * HEADDIM + p] = accF[j][r];
        }
    }
}

// ---------------- combine: sequential over chunks (elementwise, layout [n][p]) ----------------
__global__ __launch_bounds__(256) void combine_kernel(
    const float* __restrict__ Fbuf, const float* __restrict__ cumA,
    float* __restrict__ Hinit) {
    int bh = blockIdx.x;
    int tid = threadIdx.x;
    float H[16];
#pragma unroll
    for (int k = 0; k < 16; k++) H[k] = 0.f;
    for (int c = 0; c < NCHUNK; c++) {
        size_t base = (size_t)(bh * NCHUNK + c) * (HEADDIM * D_STATE);
        float pA = cumA[(size_t)(bh * NCHUNK + c) * LC + (LC - 1)];
#pragma unroll
        for (int k = 0; k < 16; k++) {
            size_t idx = base + tid + k * 256;
            Hinit[idx] = H[k];
            H[k] = fmaf(pA, H[k], Fbuf[idx]);
        }
    }
}

// ---------------- ycorr: y += cumA[t] * C_t . Hinit  (Hinit layout [n][p]) ----------------
__global__ __launch_bounds__(256) void ycorr_kernel(
    const float* __restrict__ xbc, const float* __restrict__ cumA,
    const float* __restrict__ Hinit, float* __restrict__ y) {
    int blk = blockIdx.x;
    int c = blk % NCHUNK;
    int bh = blk / NCHUNK;
    int h = bh % NHEADS, b = bh / NHEADS;
    __shared__ float Cd[LC][D_STATE + 1];
    __shared__ float Hs[D_STATE][HEADDIM + 1];   // [n][p]
    int tid = threadIdx.x;
    size_t cbase = (size_t)blk * LC;
    size_t hbase = (size_t)blk * (HEADDIM * D_STATE);
#pragma unroll
    for (int k = 0; k < 16; k++) {
        int idx = tid + k * 256;
        int r = idx >> 6, n = idx & 63;
        size_t row = (size_t)(b * SEQ + c * LC + r);
        Cd[r][n] = xbc[row * CONV_DIM + D_INNER + D_STATE + n] * cumA[cbase + r];
        Hs[r][n] = Hinit[hbase + idx];           // r plays the [n]-row role here
    }
    __syncthreads();
    int tx = tid & 15, ty = tid >> 4;
    float acc[4][4] = {};
    for (int n = 0; n < D_STATE; n++) {
        float cv[4], hv[4];
#pragma unroll
        for (int i = 0; i < 4; i++) cv[i] = Cd[ty * 4 + i][n];
#pragma unroll
        for (int j = 0; j < 4; j++) hv[j] = Hs[n][tx * 4 + j];
#pragma unroll
        for (int i = 0; i < 4; i++)
#pragma unroll
            for (int j = 0; j < 4; j++)
                acc[i][j] = fmaf(cv[i], hv[j], acc[i][j]);
    }
#pragma unroll
    for (int i = 0; i < 4; i++) {
        int tt = ty * 4 + i;
        size_t row = (size_t)(b * SEQ + c * LC + tt);
#pragma unroll
        for (int j = 0; j < 4; j++) {
            int p = tx * 4 + j;
            size_t oidx = row * D_INNER + h * HEADDIM + p;
            y[oidx] += acc[i][j];
        }
    }
}

// ---------------- gated rmsnorm -> bf16 ----------------
__global__ __launch_bounds__(256) void gatenorm_kernel(
    const float* __restrict__ y, const float* __restrict__ zx,
    const float* __restrict__ w, unsigned short* __restrict__ out) {
    int row = blockIdx.x;
    const float* z = zx + (size_t)row * ZSTR;
    const float* yr = y + (size_t)row * D_INNER;
    float g[6];
    float ss = 0.f;
#pragma unroll
    for (int e = 0; e < 6; e++) {
        int idx = threadIdx.x + e * 256;
        float zv = z[idx];
        float gv = yr[idx] * (zv * sigmoidf_(zv));
        g[e] = gv;
        ss += gv * gv;
    }
    ss = blockReduceSum<4>(ss);
    float sc = rsqrtf(ss * (1.f / D_INNER) + 1e-6f);
#pragma unroll
    for (int e = 0; e < 6; e++) {
        int idx = threadIdx.x + e * 256;
        out[(size_t)row * D_INNER + idx] = f2bf(g[e] * sc * w[idx]);
    }
}

// ---------------- launch ----------------
extern "C" void kernel_launch(void* const* d_in, const int* in_sizes, int n_in,
                              void* d_out, int out_size, void* d_ws, size_t ws_size,
                              hipStream_t stream) {
    const float* x        = (const float*)d_in[0];
    const float* x_prompt = (const float*)d_in[1];
    const float* in_base  = (const float*)d_in[2];
    const float* lA_in    = (const float*)d_in[3];
    const float* lB_in    = (const float*)d_in[4];
    const float* conv_w   = (const float*)d_in[5];
    const float* conv_b   = (const float*)d_in[6];
    const float* dt_bias  = (const float*)d_in[7];
    const float* A_log    = (const float*)d_in[8];
    const float* D_param  = (const float*)d_in[9];
    const float* gnw      = (const float*)d_in[10];
    const float* out_base = (const float*)d_in[11];
    const float* lA_out   = (const float*)d_in[12];
    const float* lB_out   = (const float*)d_in[13];
    const float* loop_nw  = (const float*)d_in[14];
    const float* gate     = (const float*)d_in[15];
    float* out = (float*)d_out;

    float* ws_f = (float*)d_ws;
    float* zx    = ws_f;                                   // 2048*3328 f32
    float* xbc   = zx    + (size_t)NROWS * ZSTR;           // 2048*1664
    float* ybuf  = xbc   + (size_t)NROWS * CONV_DIM;       // 2048*1536
    float* Fbuf  = ybuf  + (size_t)NROWS * D_INNER;        // 768*4096
    float* Hinit = Fbuf  + (size_t)BSZ * NHEADS * NCHUNK * HEADDIM * D_STATE;
    float* cumA  = Hinit + (size_t)BSZ * NHEADS * NCHUNK * HEADDIM * D_STATE; // 768*64
    unsigned short* W_in  = (unsigned short*)(cumA + (size_t)BSZ * NHEADS * NCHUNK * LC);
    unsigned short* W_out = W_in  + (size_t)NPAD * D_MODEL;
    unsigned short* hbuf  = W_out + (size_t)D_MODEL * D_INNER;
    unsigned short* ygt   = hbuf  + (size_t)NROWS * D_MODEL;

    build_w_in_kernel<<<(NPAD * D_MODEL + 255) / 256, 256, 0, stream>>>(in_base, lA_in, lB_in, W_in);
    build_w_out_kernel<<<(D_MODEL * D_INNER + 255) / 256, 256, 0, stream>>>(out_base, lA_out, lB_out, W_out);

    for (int i = 0; i < 2; i++) {   // n_loops = 2 (fixed by setup_inputs)
        const float* xsrc = (i == 0) ? x : out;
        rmsrope_kernel<<<NROWS, 384, 0, stream>>>(xsrc, loop_nw, hbuf, i);

        dim3 g1(NPAD / 128, NROWS / 128);
        gemm_bf16_kernel<<<g1, 256, 0, stream>>>(hbuf, W_in, zx, NROWS, NPAD, D_MODEL, ZSTR,
                                                 nullptr, nullptr);

        conv_kernel<<<(BSZ * SEQ * CONV_DIM + 255) / 256, 256, 0, stream>>>(zx, conv_w, conv_b, xbc);

        scan_mfma_kernel<<<BSZ * NHEADS * NCHUNK, 256, 0, stream>>>(
            xbc, zx, dt_bias, A_log, D_param, ybuf, Fbuf, cumA);
        combine_kernel<<<BSZ * NHEADS, 256, 0, stream>>>(Fbuf, cumA, Hinit);
        ycorr_kernel<<<BSZ * NHEADS * NCHUNK, 256, 0, stream>>>(xbc, cumA, Hinit, ybuf);

        gatenorm_kernel<<<NROWS, 256, 0, stream>>>(ybuf, zx, gnw, ygt);

        dim3 g2(D_MODEL / 128, NROWS / 128);
        gemm_bf16_kernel<<<g2, 256, 0, stream>>>(ygt, W_out, out, NROWS, D_MODEL, D_INNER, D_MODEL,
                                                 x_prompt, gate);
    }
}

// Round 7
// 327.726 us; speedup vs baseline: 5.9133x; 1.1743x over previous
//
#include <hip/hip_runtime.h>
#include <hip/hip_bf16.h>
#include <math.h>

#define D_MODEL 768
#define D_STATE 64
#define D_CONV 4
#define D_INNER 1536
#define HEADDIM 64
#define NHEADS 24
#define RANK 8
#define D_IN_PROJ 3224   // 2*1536 + 2*64 + 24
#define NPAD 3328        // D_IN_PROJ padded to multiple of 128
#define ZSTR 3328        // zx row stride (padded)
#define CONV_DIM 1664    // 1536 + 128
#define BSZ 2
#define SEQ 1024
#define NROWS (BSZ*SEQ)  // 2048
#define SCALE_LORA 2.0f  // 16/8
#define LC 64            // chunk length
#define NCHUNK (SEQ/LC)  // 16
#define LSTR 72          // LDS row stride (bf16) for scan kernel: 144B -> 2-way banks

typedef __attribute__((ext_vector_type(8))) short bf16x8;
typedef __attribute__((ext_vector_type(4))) float f32x4;

// ---------------- helpers ----------------

__device__ inline float waveReduceSum(float v) {
#pragma unroll
    for (int m = 32; m; m >>= 1) v += __shfl_xor(v, m, 64);
    return v;
}

template <int NWAVES>
__device__ inline float blockReduceSum(float v) {
    __shared__ float tmp[NWAVES];
    int lane = threadIdx.x & 63, wid = threadIdx.x >> 6;
    v = waveReduceSum(v);
    if (lane == 0) tmp[wid] = v;
    __syncthreads();
    float tot = 0.f;
#pragma unroll
    for (int i = 0; i < NWAVES; i++) tot += tmp[i];
    return tot;
}

__device__ inline float sigmoidf_(float x) { return 1.f / (1.f + expf(-x)); }

// float -> bf16 (round-to-nearest-even)
__device__ inline unsigned short f2bf(float f) {
    union { float f; unsigned int u; } v; v.f = f;
    unsigned int r = (v.u + 0x7fffu + ((v.u >> 16) & 1u)) >> 16;
    return (unsigned short)r;
}

__device__ inline void load_lds16(const void* g, void* l) {
    __builtin_amdgcn_global_load_lds((const __attribute__((address_space(1))) void*)g,
                                     (__attribute__((address_space(3))) void*)l, 16, 0, 0);
}

// ---------------- weight build (f32 base + LoRA -> bf16) ----------------

__global__ void build_w_in_kernel(const float* __restrict__ base,
                                  const float* __restrict__ lA,
                                  const float* __restrict__ lB,
                                  unsigned short* __restrict__ W) {  // [NPAD][D_MODEL]
    int idx = blockIdx.x * blockDim.x + threadIdx.x;
    if (idx >= NPAD * D_MODEL) return;
    int r = idx / D_MODEL, c = idx - r * D_MODEL;
    if (r >= D_IN_PROJ) { W[idx] = 0; return; }
    float s = 0.f;
#pragma unroll
    for (int k = 0; k < RANK; k++) s += lB[r * RANK + k] * lA[k * D_MODEL + c];
    W[idx] = f2bf(base[(size_t)r * D_MODEL + c] + SCALE_LORA * s);
}

__global__ void build_w_out_kernel(const float* __restrict__ base,
                                   const float* __restrict__ lA,
                                   const float* __restrict__ lB,
                                   unsigned short* __restrict__ W) { // [D_MODEL][D_INNER]
    int idx = blockIdx.x * blockDim.x + threadIdx.x;
    if (idx >= D_MODEL * D_INNER) return;
    int r = idx / D_INNER, c = idx - r * D_INNER;
    float s = 0.f;
#pragma unroll
    for (int k = 0; k < RANK; k++) s += lB[r * RANK + k] * lA[k * D_INNER + c];
    W[idx] = f2bf(base[idx] + SCALE_LORA * s);
}

// ---------------- rmsnorm + rope -> bf16 ----------------
__global__ __launch_bounds__(384) void rmsrope_kernel(
    const float* __restrict__ x, const float* __restrict__ w,
    unsigned short* __restrict__ out, int loop_i) {
    int row = blockIdx.x;
    const float* xr = x + (size_t)row * D_MODEL;
    int j = threadIdx.x;
    float x0 = xr[2 * j], x1 = xr[2 * j + 1];
    float ss = blockReduceSum<6>(x0 * x0 + x1 * x1);
    float sc = rsqrtf(ss * (1.f / D_MODEL) + 1e-6f);
    float y0 = x0 * sc * w[2 * j];
    float y1 = x1 * sc * w[2 * j + 1];
    float ang = (float)loop_i * expf((float)(2 * j) * (-9.210340371976184f / (float)D_MODEL));
    float c = cosf(ang), sn = sinf(ang);
    unsigned short* orow = out + (size_t)row * D_MODEL;
    orow[2 * j]     = f2bf(y0 * c - y1 * sn);
    orow[2 * j + 1] = f2bf(y1 * c + y0 * sn);
}

// ---------------- bf16 MFMA GEMM, 2-phase prefetch dbuf + swizzled LDS ----------------
// C[M][Cstride] (+)= A[M][K] . B[N][K]^T over K-range [z*Ks, (z+1)*Ks)
// mode 0: plain store; mode 1: atomicAdd (split-K)
// Swizzle: LDS slot (row, u16) holds global (row, u16 ^ (row&7)); read XORs back.
__global__ __launch_bounds__(256) void gemm_pipe_kernel(
    const unsigned short* __restrict__ A,
    const unsigned short* __restrict__ B,
    float* __restrict__ C, int M, int N, int K, int Cstride,
    int Ks, int mode) {
    __shared__ unsigned short lsA[2][128 * 64];
    __shared__ unsigned short lsB[2][128 * 64];
    int t = threadIdx.x;
    int w = t >> 6, lane = t & 63;
    int n0 = blockIdx.x * 128, m0 = blockIdx.y * 128;
    int kbase = blockIdx.z * Ks;
    int wr = w >> 1, wc = w & 1;
    f32x4 acc[4][4];
#pragma unroll
    for (int i = 0; i < 4; i++)
#pragma unroll
        for (int j = 0; j < 4; j++) acc[i][j] = (f32x4){0.f, 0.f, 0.f, 0.f};

#define STAGE(bi, kk0)                                                           \
    {                                                                            \
        _Pragma("unroll")                                                        \
        for (int o = 0; o < 4; o++) {                                            \
            int s = o * 256 + t;                                                 \
            int row = s >> 3, u = s & 7;                                         \
            int usrc = (u ^ (row & 7)) << 3;                                     \
            unsigned short* la = &lsA[bi][(size_t)(o * 256 + (t & ~63)) * 8];    \
            unsigned short* lb = &lsB[bi][(size_t)(o * 256 + (t & ~63)) * 8];    \
            load_lds16(&A[(size_t)(m0 + row) * K + (kk0) + usrc], la);           \
            load_lds16(&B[(size_t)(n0 + row) * K + (kk0) + usrc], lb);           \
        }                                                                        \
    }

    int nk = Ks >> 6;
    STAGE(0, kbase);
    __syncthreads();           // drains vmcnt(0): buffer 0 ready
    int cur = 0;
    for (int ks = 0; ks < nk; ks++) {
        if (ks + 1 < nk) STAGE(cur ^ 1, kbase + (ks + 1) * 64);   // prefetch next
#pragma unroll
        for (int kk = 0; kk < 2; kk++) {
            bf16x8 af[4], bfr[4];
            int u_t = kk * 4 + (lane >> 4);
            int kof = (u_t ^ (lane & 7)) << 3;    // swizzled read column
#pragma unroll
            for (int i = 0; i < 4; i++) {
                int row = wr * 64 + i * 16 + (lane & 15);
                af[i] = *(const bf16x8*)&lsA[cur][row * 64 + kof];
            }
#pragma unroll
            for (int j = 0; j < 4; j++) {
                int row = wc * 64 + j * 16 + (lane & 15);
                bfr[j] = *(const bf16x8*)&lsB[cur][row * 64 + kof];
            }
#pragma unroll
            for (int i = 0; i < 4; i++)
#pragma unroll
                for (int j = 0; j < 4; j++)
                    acc[i][j] = __builtin_amdgcn_mfma_f32_16x16x32_bf16(af[i], bfr[j], acc[i][j], 0, 0, 0);
        }
        __syncthreads();       // all waves done with cur; prefetch (vmcnt 0) landed
        cur ^= 1;
    }
#undef STAGE

#pragma unroll
    for (int i = 0; i < 4; i++) {
#pragma unroll
        for (int j = 0; j < 4; j++) {
#pragma unroll
            for (int r = 0; r < 4; r++) {
                int row = m0 + wr * 64 + i * 16 + (lane >> 4) * 4 + r;
                int col = n0 + wc * 64 + j * 16 + (lane & 15);
                float v = acc[i][j][r];
                if (mode) atomicAdd(&C[(size_t)row * Cstride + col], v);
                else      C[(size_t)row * Cstride + col] = v;
            }
        }
    }
}

// ---------------- GEMM2 epilogue init: out = gate * x_prompt ----------------
__global__ void epilog_init_kernel(const float* __restrict__ xp,
                                   const float* __restrict__ gate,
                                   float* __restrict__ out) {
    int idx = blockIdx.x * blockDim.x + threadIdx.x;   // float4 index
    if (idx >= NROWS * D_MODEL / 4) return;
    float4 xv = ((const float4*)xp)[idx];
    int n0 = (idx * 4) % D_MODEL;
    float4 g = *(const float4*)&gate[n0];
    float4 o = make_float4(g.x * xv.x, g.y * xv.y, g.z * xv.z, g.w * xv.w);
    ((float4*)out)[idx] = o;
}

// ---------------- depthwise causal conv + silu ----------------
__global__ void conv_kernel(const float* __restrict__ zx, const float* __restrict__ cw,
                            const float* __restrict__ cb, float* __restrict__ xbc) {
    int idx = blockIdx.x * blockDim.x + threadIdx.x;
    if (idx >= BSZ * SEQ * CONV_DIM) return;
    int c = idx % CONV_DIM;
    int l = (idx / CONV_DIM) % SEQ;
    int b = idx / (CONV_DIM * SEQ);
    const float* base = zx + (size_t)b * SEQ * ZSTR + D_INNER + c;
    float acc = cb[c];
#pragma unroll
    for (int t = 0; t < 4; t++) {
        int ll = l - 3 + t;
        if (ll >= 0) acc = fmaf(cw[c * 4 + t], base[(size_t)ll * ZSTR], acc);
    }
    xbc[idx] = acc * sigmoidf_(acc);
}

// ---------------- MFMA chunked scan ----------------
__global__ __launch_bounds__(256) void scan_mfma_kernel(
    const float* __restrict__ xbc,   // [NROWS][CONV_DIM]
    const float* __restrict__ zx,    // [NROWS][ZSTR]
    const float* __restrict__ dt_bias,
    const float* __restrict__ A_log,
    const float* __restrict__ Dp,
    float* __restrict__ y,           // [NROWS][D_INNER]
    float* __restrict__ Fbuf,        // [blk][n][p]
    float* __restrict__ cumA) {      // [blk][LC]
    __shared__ unsigned short Cc[64][LSTR];
    __shared__ unsigned short Bb[64][LSTR];
    __shared__ unsigned short Xt[64][LSTR];   // Xt[p][u]
    __shared__ unsigned short Bw[64][LSTR];   // Bw[n][u]
    __shared__ unsigned short Mm[64][LSTR];
    __shared__ float s_lds[64];
    __shared__ float dt_lds[64];

    int blk = blockIdx.x;
    int c = blk % NCHUNK;
    int bh = blk / NCHUNK;
    int h = bh % NHEADS, b = bh / NHEADS;
    int tid = threadIdx.x;
    int w = tid >> 6, lane = tid & 63;
    const int t0 = c * LC;

    if (w == 0) {
        int t = lane;
        size_t row = (size_t)(b * SEQ + t0 + t);
        float raw = zx[row * ZSTR + (D_INNER + CONV_DIM) + h] + dt_bias[h];
        float dt_t = raw > 20.f ? raw : log1pf(expf(raw));
        float s = dt_t * (-expf(A_log[h]));
#pragma unroll
        for (int off = 1; off < 64; off <<= 1) {
            float v = __shfl_up(s, off, 64);
            if (lane >= off) s += v;
        }
        s_lds[t] = s;
        dt_lds[t] = dt_t;
        cumA[(size_t)blk * LC + t] = expf(s);
    }

    float breg[16];
#pragma unroll
    for (int k = 0; k < 16; k++) {
        int idx = k * 256 + tid;
        int r = idx >> 6, ci = idx & 63;
        size_t row = (size_t)(b * SEQ + t0 + r) * CONV_DIM;
        float cv = xbc[row + D_INNER + D_STATE + ci];
        float bv = xbc[row + D_INNER + ci];
        float xv = xbc[row + h * HEADDIM + ci];
        Cc[r][ci] = f2bf(cv);
        Bb[r][ci] = f2bf(bv);
        Xt[ci][r] = f2bf(xv);
        breg[k] = bv;
    }
    __syncthreads();

    float s63 = s_lds[63];
#pragma unroll
    for (int k = 0; k < 16; k++) {
        int idx = k * 256 + tid;
        int r = idx >> 6, ci = idx & 63;
        float wu = expf(s63 - s_lds[r]) * dt_lds[r];
        Bw[ci][r] = f2bf(breg[k] * wu);
    }

    f32x4 accG[4];
#pragma unroll
    for (int j = 0; j < 4; j++) accG[j] = (f32x4){0.f, 0.f, 0.f, 0.f};
#pragma unroll
    for (int kk = 0; kk < 2; kk++) {
        int kof = kk * 32 + (lane >> 4) * 8;
        bf16x8 afr = *(const bf16x8*)&Cc[16 * w + (lane & 15)][kof];
#pragma unroll
        for (int j = 0; j < 4; j++) {
            bf16x8 bfr = *(const bf16x8*)&Bb[16 * j + (lane & 15)][kof];
            accG[j] = __builtin_amdgcn_mfma_f32_16x16x32_bf16(afr, bfr, accG[j], 0, 0, 0);
        }
    }
#pragma unroll
    for (int j = 0; j < 4; j++) {
#pragma unroll
        for (int r = 0; r < 4; r++) {
            int t = 16 * w + (lane >> 4) * 4 + r;
            int u = 16 * j + (lane & 15);
            float v = 0.f;
            if (u <= t) v = accG[j][r] * dt_lds[u] * expf(s_lds[t] - s_lds[u]);
            Mm[t][u] = f2bf(v);
        }
    }
    __syncthreads();

    f32x4 accY[4];
#pragma unroll
    for (int j = 0; j < 4; j++) accY[j] = (f32x4){0.f, 0.f, 0.f, 0.f};
#pragma unroll
    for (int kk = 0; kk < 2; kk++) {
        int kof = kk * 32 + (lane >> 4) * 8;
        bf16x8 afr = *(const bf16x8*)&Mm[16 * w + (lane & 15)][kof];
#pragma unroll
        for (int j = 0; j < 4; j++) {
            bf16x8 bfr = *(const bf16x8*)&Xt[16 * j + (lane & 15)][kof];
            accY[j] = __builtin_amdgcn_mfma_f32_16x16x32_bf16(afr, bfr, accY[j], 0, 0, 0);
        }
    }
    float D_h = Dp[h];
#pragma unroll
    for (int j = 0; j < 4; j++) {
#pragma unroll
        for (int r = 0; r < 4; r++) {
            int t = 16 * w + (lane >> 4) * 4 + r;
            int p = 16 * j + (lane & 15);
            size_t row = (size_t)(b * SEQ + t0 + t);
            float xv = xbc[row * CONV_DIM + h * HEADDIM + p];
            y[row * D_INNER + h * HEADDIM + p] = accY[j][r] + D_h * xv;
        }
    }

    f32x4 accF[4];
#pragma unroll
    for (int j = 0; j < 4; j++) accF[j] = (f32x4){0.f, 0.f, 0.f, 0.f};
#pragma unroll
    for (int kk = 0; kk < 2; kk++) {
        int kof = kk * 32 + (lane >> 4) * 8;
        bf16x8 afr = *(const bf16x8*)&Bw[16 * w + (lane & 15)][kof];
#pragma unroll
        for (int j = 0; j < 4; j++) {
            bf16x8 bfr = *(const bf16x8*)&Xt[16 * j + (lane & 15)][kof];
            accF[j] = __builtin_amdgcn_mfma_f32_16x16x32_bf16(afr, bfr, accF[j], 0, 0, 0);
        }
    }
#pragma unroll
    for (int j = 0; j < 4; j++) {
#pragma unroll
        for (int r = 0; r < 4; r++) {
            int n = 16 * w + (lane >> 4) * 4 + r;
            int p = 16 * j + (lane & 15);
            Fbuf[(size_t)blk * (HEADDIM * D_STATE) + n * HEADDIM + p] = accF[j][r];
        }
    }
}

// ---------------- combine: parallel over (bh, np-group); chain over 16 chunks ----------------
__global__ __launch_bounds__(256) void combine_kernel(
    const float* __restrict__ Fbuf, const float* __restrict__ cumA,
    float* __restrict__ Hinit) {
    int bh = blockIdx.x >> 4;
    int np = (blockIdx.x & 15) * 256 + threadIdx.x;
    float H = 0.f;
#pragma unroll
    for (int c = 0; c < NCHUNK; c++) {
        size_t idx = (size_t)(bh * NCHUNK + c) * (HEADDIM * D_STATE) + np;
        float pA = cumA[(size_t)(bh * NCHUNK + c) * LC + (LC - 1)];
        Hinit[idx] = H;
        H = fmaf(pA, H, Fbuf[idx]);
    }
}

// ---------------- ycorr: y += cumA[t] * C_t . Hinit  (Hinit layout [n][p]) ----------------
__global__ __launch_bounds__(256) void ycorr_kernel(
    const float* __restrict__ xbc, const float* __restrict__ cumA,
    const float* __restrict__ Hinit, float* __restrict__ y) {
    int blk = blockIdx.x;
    int c = blk % NCHUNK;
    int bh = blk / NCHUNK;
    int h = bh % NHEADS, b = bh / NHEADS;
    __shared__ float Cd[LC][D_STATE + 1];
    __shared__ float Hs[D_STATE][HEADDIM + 1];
    int tid = threadIdx.x;
    size_t cbase = (size_t)blk * LC;
    size_t hbase = (size_t)blk * (HEADDIM * D_STATE);
#pragma unroll
    for (int k = 0; k < 16; k++) {
        int idx = tid + k * 256;
        int r = idx >> 6, n = idx & 63;
        size_t row = (size_t)(b * SEQ + c * LC + r);
        Cd[r][n] = xbc[row * CONV_DIM + D_INNER + D_STATE + n] * cumA[cbase + r];
        Hs[r][n] = Hinit[hbase + idx];
    }
    __syncthreads();
    int tx = tid & 15, ty = tid >> 4;
    float acc[4][4] = {};
    for (int n = 0; n < D_STATE; n++) {
        float cv[4], hv[4];
#pragma unroll
        for (int i = 0; i < 4; i++) cv[i] = Cd[ty * 4 + i][n];
#pragma unroll
        for (int j = 0; j < 4; j++) hv[j] = Hs[n][tx * 4 + j];
#pragma unroll
        for (int i = 0; i < 4; i++)
#pragma unroll
            for (int j = 0; j < 4; j++)
                acc[i][j] = fmaf(cv[i], hv[j], acc[i][j]);
    }
#pragma unroll
    for (int i = 0; i < 4; i++) {
        int tt = ty * 4 + i;
        size_t row = (size_t)(b * SEQ + c * LC + tt);
#pragma unroll
        for (int j = 0; j < 4; j++) {
            int p = tx * 4 + j;
            size_t oidx = row * D_INNER + h * HEADDIM + p;
            y[oidx] += acc[i][j];
        }
    }
}

// ---------------- gated rmsnorm -> bf16 ----------------
__global__ __launch_bounds__(256) void gatenorm_kernel(
    const float* __restrict__ y, const float* __restrict__ zx,
    const float* __restrict__ w, unsigned short* __restrict__ out) {
    int row = blockIdx.x;
    const float* z = zx + (size_t)row * ZSTR;
    const float* yr = y + (size_t)row * D_INNER;
    float g[6];
    float ss = 0.f;
#pragma unroll
    for (int e = 0; e < 6; e++) {
        int idx = threadIdx.x + e * 256;
        float zv = z[idx];
        float gv = yr[idx] * (zv * sigmoidf_(zv));
        g[e] = gv;
        ss += gv * gv;
    }
    ss = blockReduceSum<4>(ss);
    float sc = rsqrtf(ss * (1.f / D_INNER) + 1e-6f);
#pragma unroll
    for (int e = 0; e < 6; e++) {
        int idx = threadIdx.x + e * 256;
        out[(size_t)row * D_INNER + idx] = f2bf(g[e] * sc * w[idx]);
    }
}

// ---------------- launch ----------------
extern "C" void kernel_launch(void* const* d_in, const int* in_sizes, int n_in,
                              void* d_out, int out_size, void* d_ws, size_t ws_size,
                              hipStream_t stream) {
    const float* x        = (const float*)d_in[0];
    const float* x_prompt = (const float*)d_in[1];
    const float* in_base  = (const float*)d_in[2];
    const float* lA_in    = (const float*)d_in[3];
    const float* lB_in    = (const float*)d_in[4];
    const float* conv_w   = (const float*)d_in[5];
    const float* conv_b   = (const float*)d_in[6];
    const float* dt_bias  = (const float*)d_in[7];
    const float* A_log    = (const float*)d_in[8];
    const float* D_param  = (const float*)d_in[9];
    const float* gnw      = (const float*)d_in[10];
    const float* out_base = (const float*)d_in[11];
    const float* lA_out   = (const float*)d_in[12];
    const float* lB_out   = (const float*)d_in[13];
    const float* loop_nw  = (const float*)d_in[14];
    const float* gate     = (const float*)d_in[15];
    float* out = (float*)d_out;

    float* ws_f = (float*)d_ws;
    float* zx    = ws_f;                                   // 2048*3328 f32
    float* xbc   = zx    + (size_t)NROWS * ZSTR;           // 2048*1664
    float* ybuf  = xbc   + (size_t)NROWS * CONV_DIM;       // 2048*1536
    float* Fbuf  = ybuf  + (size_t)NROWS * D_INNER;        // 768*4096
    float* Hinit = Fbuf  + (size_t)BSZ * NHEADS * NCHUNK * HEADDIM * D_STATE;
    float* cumA  = Hinit + (size_t)BSZ * NHEADS * NCHUNK * HEADDIM * D_STATE; // 768*64
    unsigned short* W_in  = (unsigned short*)(cumA + (size_t)BSZ * NHEADS * NCHUNK * LC);
    unsigned short* W_out = W_in  + (size_t)NPAD * D_MODEL;
    unsigned short* hbuf  = W_out + (size_t)D_MODEL * D_INNER;
    unsigned short* ygt   = hbuf  + (size_t)NROWS * D_MODEL;

    build_w_in_kernel<<<(NPAD * D_MODEL + 255) / 256, 256, 0, stream>>>(in_base, lA_in, lB_in, W_in);
    build_w_out_kernel<<<(D_MODEL * D_INNER + 255) / 256, 256, 0, stream>>>(out_base, lA_out, lB_out, W_out);

    for (int i = 0; i < 2; i++) {   // n_loops = 2 (fixed by setup_inputs)
        const float* xsrc = (i == 0) ? x : out;
        rmsrope_kernel<<<NROWS, 384, 0, stream>>>(xsrc, loop_nw, hbuf, i);

        // GEMM1: zx = hbuf . W_in^T   (M=2048, N=3328, K=768, no split)
        dim3 g1(NPAD / 128, NROWS / 128, 1);
        gemm_pipe_kernel<<<g1, 256, 0, stream>>>(hbuf, W_in, zx, NROWS, NPAD, D_MODEL, ZSTR,
                                                 D_MODEL, 0);

        conv_kernel<<<(BSZ * SEQ * CONV_DIM + 255) / 256, 256, 0, stream>>>(zx, conv_w, conv_b, xbc);

        scan_mfma_kernel<<<BSZ * NHEADS * NCHUNK, 256, 0, stream>>>(
            xbc, zx, dt_bias, A_log, D_param, ybuf, Fbuf, cumA);
        combine_kernel<<<BSZ * NHEADS * 16, 256, 0, stream>>>(Fbuf, cumA, Hinit);
        ycorr_kernel<<<BSZ * NHEADS * NCHUNK, 256, 0, stream>>>(xbc, cumA, Hinit, ybuf);

        gatenorm_kernel<<<NROWS, 256, 0, stream>>>(ybuf, zx, gnw, ygt);

        // GEMM2: out = ygt . W_out^T + gate*x_prompt  (split-K=4, atomic)
        epilog_init_kernel<<<(NROWS * D_MODEL / 4 + 255) / 256, 256, 0, stream>>>(x_prompt, gate, out);
        dim3 g2(D_MODEL / 128, NROWS / 128, 4);
        gemm_pipe_kernel<<<g2, 256, 0, stream>>>(ygt, W_out, out, NROWS, D_MODEL, D_INNER, D_MODEL,
                                                 D_INNER / 4, 1);
    }
}